// Round 1
// baseline (746.076 us; speedup 1.0000x reference)
//
#include <hip/hip_runtime.h>
#include <stdint.h>

#define B_ 8
#define P_ 2048
#define K_ 20
#define N_ (B_*P_)     // 16384
#define M_ (B_*K_)     // 160
#define C 128
#define E_ (N_*K_)     // 327680
#define EPS_ 1e-5f

typedef unsigned short u16;
typedef unsigned int u32;
typedef __attribute__((ext_vector_type(8))) short short8;
typedef __attribute__((ext_vector_type(4))) float floatx4;

__device__ __forceinline__ float bf2f(u16 u){
    union { u32 i; float f; } v; v.i = ((u32)u) << 16; return v.f;
}
__device__ __forceinline__ u16 f2bf(float f){
    union { float f; u32 i; } v; v.f = f;
    u32 r = ((v.i >> 16) & 1u) + 0x7fffu;
    return (u16)((v.i + r) >> 16);
}

// ---------------------------------------------------------------------------
// prep: Cq = aW1@Wq [128,64], Ck = aW1@Wk, dq = aW1@bq + ab1, dk = aW1@bk,
//       bf16 copies of pW2, aW1, aW2
// grid 68 x 256
__global__ __launch_bounds__(256)
void prep_weights(const float* __restrict__ Wq, const float* __restrict__ bq,
                  const float* __restrict__ Wk, const float* __restrict__ bk,
                  const float* __restrict__ aW1, const float* __restrict__ ab1,
                  const float* __restrict__ pW2, const float* __restrict__ aW2,
                  float* __restrict__ Cq, float* __restrict__ Ck,
                  float* __restrict__ dq, float* __restrict__ dk,
                  u16* __restrict__ Wb0, u16* __restrict__ Wb1, u16* __restrict__ Wb2)
{
    int tid = threadIdx.x, blk = blockIdx.x;
    if (blk < 32) {
        int idx = blk*256 + tid; int o = idx >> 6, i = idx & 63;
        float s = 0.f;
        for (int cc = 0; cc < 128; ++cc) s = fmaf(aW1[o*128+cc], Wq[cc*64+i], s);
        Cq[idx] = s;
    } else if (blk < 64) {
        int idx = (blk-32)*256 + tid; int o = idx >> 6, i = idx & 63;
        float s = 0.f;
        for (int cc = 0; cc < 128; ++cc) s = fmaf(aW1[o*128+cc], Wk[cc*64+i], s);
        Ck[idx] = s;
    } else if (blk == 64) {
        if (tid < 128) {
            float s = ab1[tid];
            for (int cc = 0; cc < 128; ++cc) s = fmaf(aW1[tid*128+cc], bq[cc], s);
            dq[tid] = s;
        } else {
            int o = tid - 128;
            float s = 0.f;
            for (int cc = 0; cc < 128; ++cc) s = fmaf(aW1[o*128+cc], bk[cc], s);
            dk[o] = s;
        }
    } else {
        const float* src = (blk == 65) ? pW2 : (blk == 66) ? aW1 : aW2;
        u16* dst = (blk == 65) ? Wb0 : (blk == 66) ? Wb1 : Wb2;
        for (int i = tid; i < 128*128; i += 256) dst[i] = f2bf(src[i]);
    }
}

// ---------------------------------------------------------------------------
// knn (k=1 vs each graph's 20 fps nodes) + kernel-weighted scatter into
// gacc[m][68]: [0]=cnt, [1..3]=sum ek*pos, [4..67]=sum ek*x.  grid 64 x 256
__global__ __launch_bounds__(256)
void knn_scatter(const float* __restrict__ pos, const float* __restrict__ x,
                 const int* __restrict__ fps_idx, float* __restrict__ gacc)
{
    __shared__ float fpos[K_][3];
    __shared__ float accL[K_][68];
    int tid = threadIdx.x;
    int b = blockIdx.x >> 3;              // 8 blocks per graph (2048/256)
    if (tid < K_*3) {
        int k = tid / 3, d = tid % 3;
        fpos[k][d] = pos[fps_idx[b*K_+k]*3 + d];
    }
    for (int i = tid; i < K_*68; i += 256) ((float*)accL)[i] = 0.f;
    __syncthreads();
    int p = blockIdx.x*256 + tid;
    float px = pos[p*3], py = pos[p*3+1], pz = pos[p*3+2];
    float best = 1e30f; int kb = 0;
    #pragma unroll
    for (int k = 0; k < K_; ++k) {
        float dx = px - fpos[k][0], dy = py - fpos[k][1], dz = pz - fpos[k][2];
        float d2 = dx*dx + dy*dy + dz*dz;
        if (d2 < best) { best = d2; kb = k; }   // strict <: keep first (argmin)
    }
    float ek = 1.0f / (1.0f + 5.0f*best);
    atomicAdd(&accL[kb][0], 1.0f);
    atomicAdd(&accL[kb][1], ek*px);
    atomicAdd(&accL[kb][2], ek*py);
    atomicAdd(&accL[kb][3], ek*pz);
    for (int cI = 0; cI < 64; ++cI) atomicAdd(&accL[kb][4+cI], ek*x[p*64+cI]);
    __syncthreads();
    for (int i = tid; i < K_*68; i += 256) {
        int k = i / 68, f = i % 68;
        atomicAdd(&gacc[(b*K_+k)*68 + f], accL[k][f]);
    }
}

// divide sums by max(cnt,1) in place. grid 160 x 128
__global__ void fps_finalize(float* __restrict__ gacc)
{
    int m = blockIdx.x, t = threadIdx.x;
    float c = gacc[m*68]; c = c > 1.f ? c : 1.f;
    if (t >= 1 && t < 68) gacc[m*68+t] /= c;
}

// Ak2[m] = Ck@fps_x + dk ; xv[m] = Wv@fps_x + bv. grid 160 x 128
__global__ __launch_bounds__(128)
void proj_m(const float* __restrict__ gacc, const float* __restrict__ Ck,
            const float* __restrict__ dk, const float* __restrict__ Wv,
            const float* __restrict__ bv, float* __restrict__ Ak2,
            float* __restrict__ xv)
{
    int m = blockIdx.x, o = threadIdx.x;
    const float* fx = gacc + m*68 + 4;
    float a = dk[o], v = bv[o];
    for (int i = 0; i < 64; ++i) {
        float xi = fx[i];
        a = fmaf(Ck[o*64+i], xi, a);
        v = fmaf(Wv[o*64+i], xi, v);
    }
    Ak2[m*C+o] = a; xv[m*C+o] = v;
}

// Aq2[p] = Cq@x[p] + dq. grid 8192 x 256 (2 points/block)
__global__ __launch_bounds__(256)
void proj_q(const float* __restrict__ x, const float* __restrict__ Cq,
            const float* __restrict__ dq, float* __restrict__ Aq2)
{
    __shared__ float xs[2][64];
    int tid = threadIdx.x;
    int p0 = blockIdx.x*2;
    if (tid < 128) xs[tid>>6][tid&63] = x[(p0 + (tid>>6))*64 + (tid&63)];
    __syncthreads();
    int pl = tid >> 7, o = tid & 127;
    float a = dq[o];
    const float* cq = Cq + o*64;
    const float* xr = xs[pl];
    #pragma unroll
    for (int i = 0; i < 64; i += 4) {
        a = fmaf(cq[i],   xr[i],   a);
        a = fmaf(cq[i+1], xr[i+1], a);
        a = fmaf(cq[i+2], xr[i+2], a);
        a = fmaf(cq[i+3], xr[i+3], a);
    }
    Aq2[(p0+pl)*C + o] = a;
}

// ---------------------------------------------------------------------------
// z1[e,c] = pW1[c]·rel(e) + pb1[c]  (3-wide), stored bf16; BN1 stats fused.
// grid 1280 x 256 (256 edges/block)
__global__ __launch_bounds__(256)
void z1_stats(const float* __restrict__ pos, const float* __restrict__ gacc,
              const float* __restrict__ pW1, const float* __restrict__ pb1,
              u16* __restrict__ z1, float* __restrict__ sums)
{
    __shared__ float ls[2][C];
    int tid = threadIdx.x;
    if (tid < C) { ls[0][tid] = 0.f; ls[1][tid] = 0.f; }
    __syncthreads();
    int c = tid & 127, eo = tid >> 7;
    float w0 = pW1[c*3], w1 = pW1[c*3+1], w2 = pW1[c*3+2], bb = pb1[c];
    int e0 = blockIdx.x * 256;
    float s = 0.f, sq = 0.f;
    for (int j = 0; j < 128; ++j) {
        int e = e0 + j*2 + eo;
        int p = e / 20; int k = e - p*20; int m = (p >> 11)*20 + k;
        float r0 = pos[p*3]   - gacc[m*68+1];
        float r1 = pos[p*3+1] - gacc[m*68+2];
        float r2 = pos[p*3+2] - gacc[m*68+3];
        float z = fmaf(w0, r0, fmaf(w1, r1, fmaf(w2, r2, bb)));
        z1[(size_t)e*C + c] = f2bf(z);
        s += z; sq += z*z;
    }
    atomicAdd(&ls[0][c], s); atomicAdd(&ls[1][c], sq);
    __syncthreads();
    if (tid < C) { atomicAdd(&sums[tid], ls[0][tid]); atomicAdd(&sums[C+tid], ls[1][tid]); }
}

// per-channel sum / sumsq of a bf16 [E,128] buffer. grid 1280 x 256
__global__ __launch_bounds__(256)
void stats_kernel(const u16* __restrict__ z, float* __restrict__ sums)
{
    __shared__ float ls[2][C];
    int tid = threadIdx.x;
    if (tid < C) { ls[0][tid] = 0.f; ls[1][tid] = 0.f; }
    __syncthreads();
    int c2 = (tid & 63)*2;
    int eo = tid >> 6;
    int e0 = blockIdx.x * 256;
    float s0 = 0.f, s1 = 0.f, q0 = 0.f, q1 = 0.f;
    for (int j = 0; j < 64; ++j) {
        int e = e0 + j*4 + eo;
        u32 w = *(const u32*)(z + (size_t)e*C + c2);
        float a = bf2f((u16)(w & 0xffffu));
        float b = bf2f((u16)(w >> 16));
        s0 += a; q0 += a*a; s1 += b; q1 += b*b;
    }
    atomicAdd(&ls[0][c2], s0);  atomicAdd(&ls[0][c2+1], s1);
    atomicAdd(&ls[1][c2], q0);  atomicAdd(&ls[1][c2+1], q1);
    __syncthreads();
    if (tid < C) { atomicAdd(&sums[tid], ls[0][tid]); atomicAdd(&sums[C+tid], ls[1][tid]); }
}

// scale = g * rsqrt(var+eps); shift = be - mean*scale. 1 x 128
__global__ void finalize_stats(const float* __restrict__ sums,
                               const float* __restrict__ g, const float* __restrict__ be,
                               float* __restrict__ scale, float* __restrict__ shift)
{
    int c = threadIdx.x;
    if (c < C) {
        float mean = sums[c] * (1.0f/E_);
        float var  = sums[C+c] * (1.0f/E_) - mean*mean;
        float sc = g[c] * rsqrtf(var + EPS_);
        scale[c] = sc;
        shift[c] = be[c] - mean*sc;
    }
}

// ---------------------------------------------------------------------------
// zout[e,:] = relu(zin[e,:]*scale+shift) @ Wbᵀ  (+ bias[col]) (+ Aq2[p]-Ak2[m])
// bf16 MFMA 16x16x32, 64 rows/block, 4 waves x (16 rows x 128 cols).
// Row-disjoint => safe in place (zin == zout). grid 5120 x 256
__global__ __launch_bounds__(256)
void gemm_bn(const u16* __restrict__ zin, u16* __restrict__ zout,
             const u16* __restrict__ Wb,
             const float* __restrict__ scale, const float* __restrict__ shift,
             const float* __restrict__ bias,
             const float* __restrict__ rowq, const float* __restrict__ rowk)
{
    __shared__ float s_sc[C], s_sh[C];
    __shared__ u16 s_out[4][16][136];          // 272B row stride: 16B aligned
    int tid = threadIdx.x;
    if (tid < C) { s_sc[tid] = scale[tid]; s_sh[tid] = shift[tid]; }
    __syncthreads();
    const int wave = tid >> 6, lane = tid & 63;
    const int L = lane & 15, q = lane >> 4;
    const int wrow = blockIdx.x*64 + wave*16;  // wave's first edge row
    const u16* aptr = zin + (size_t)(wrow + L)*C + q*8;

    floatx4 acc[8];
    #pragma unroll
    for (int ct = 0; ct < 8; ++ct) acc[ct] = (floatx4){0.f,0.f,0.f,0.f};

    #pragma unroll
    for (int ks = 0; ks < 4; ++ks) {
        short8 ar = *(const short8*)(aptr + ks*32);
        int ch0 = ks*32 + q*8;
        floatx4 sc0 = *(const floatx4*)&s_sc[ch0];
        floatx4 sc1 = *(const floatx4*)&s_sc[ch0+4];
        floatx4 sh0 = *(const floatx4*)&s_sh[ch0];
        floatx4 sh1 = *(const floatx4*)&s_sh[ch0+4];
        short8 af;
        #pragma unroll
        for (int j = 0; j < 4; ++j) {
            float f = fmaf(bf2f((u16)ar[j]), sc0[j], sh0[j]);
            f = f > 0.f ? f : 0.f;
            af[j] = (short)f2bf(f);
        }
        #pragma unroll
        for (int j = 0; j < 4; ++j) {
            float f = fmaf(bf2f((u16)ar[4+j]), sc1[j], sh1[j]);
            f = f > 0.f ? f : 0.f;
            af[4+j] = (short)f2bf(f);
        }
        #pragma unroll
        for (int ct = 0; ct < 8; ++ct) {
            short8 bfr = *(const short8*)(Wb + (ct*16+L)*C + ks*32 + q*8);
            acc[ct] = __builtin_amdgcn_mfma_f32_16x16x32_bf16(af, bfr, acc[ct], 0, 0, 0);
        }
    }

    // epilogue: +bias, +Aq2[p]-Ak2[m], bf16, LDS re-tile for coalesced store
    int pp[4], mm[4];
    if (rowq) {
        #pragma unroll
        for (int r = 0; r < 4; ++r) {
            int e = wrow + q*4 + r;
            int p = e / 20; int k = e - p*20;
            pp[r] = p; mm[r] = (p >> 11)*20 + k;
        }
    }
    #pragma unroll
    for (int ct = 0; ct < 8; ++ct) {
        int col = ct*16 + L;
        float bb = bias ? bias[col] : 0.f;
        #pragma unroll
        for (int r = 0; r < 4; ++r) {
            float z = acc[ct][r] + bb;
            if (rowq) z += rowq[pp[r]*C + col] - rowk[mm[r]*C + col];
            s_out[wave][q*4+r][col] = f2bf(z);
        }
    }
    __syncthreads();
    #pragma unroll
    for (int it = 0; it < 4; ++it) {
        int rr = it*4 + q;
        short8 v = *(const short8*)&s_out[wave][rr][L*8];
        *(short8*)(zout + (size_t)(wrow + rr)*C + L*8) = v;
    }
}

// ---------------------------------------------------------------------------
// final: alpha = softmax_k(relu(affine4(za2))); delta = relu(affine2(z2));
// out[p,c] = sum_k alpha * (xv[m,c] + delta). grid 8192 x 256 (2 points/block)
__global__ __launch_bounds__(256)
void final_kernel(const u16* __restrict__ z2, const u16* __restrict__ za2,
                  const float* __restrict__ sc2, const float* __restrict__ sh2,
                  const float* __restrict__ sc4, const float* __restrict__ sh4,
                  const float* __restrict__ xv, float* __restrict__ out)
{
    int tid = threadIdx.x;
    int p = blockIdx.x*2 + (tid >> 7);
    int c = tid & 127;
    int b = p >> 11;
    float S2 = sc2[c], H2 = sh2[c], S4 = sc4[c], H4 = sh4[c];
    float av[K_], dv[K_];
    size_t ebase = (size_t)p * K_;
    float mx = -1e30f;
    #pragma unroll
    for (int k = 0; k < K_; ++k) {
        size_t e = ebase + k;
        float a = fmaf(bf2f(za2[e*C + c]), S4, H4); a = a > 0.f ? a : 0.f;
        av[k] = a; if (a > mx) mx = a;
        float d = fmaf(bf2f(z2[e*C + c]), S2, H2); d = d > 0.f ? d : 0.f;
        dv[k] = d;
    }
    float ssum = 0.f;
    #pragma unroll
    for (int k = 0; k < K_; ++k) { av[k] = __expf(av[k] - mx); ssum += av[k]; }
    float inv = 1.0f / ssum;
    float o = 0.f;
    #pragma unroll
    for (int k = 0; k < K_; ++k) {
        float v = xv[(b*K_+k)*C + c] + dv[k];
        o = fmaf(av[k]*inv, v, o);
    }
    out[(size_t)p*C + c] = o;
}

// ---------------------------------------------------------------------------
extern "C" void kernel_launch(void* const* d_in, const int* in_sizes, int n_in,
                              void* d_out, int out_size, void* d_ws, size_t ws_size,
                              hipStream_t stream)
{
    const float* x    = (const float*)d_in[0];
    const float* pos  = (const float*)d_in[1];
    const float* Wq   = (const float*)d_in[2];
    const float* bq   = (const float*)d_in[3];
    const float* Wk   = (const float*)d_in[4];
    const float* bk   = (const float*)d_in[5];
    const float* Wv   = (const float*)d_in[6];
    const float* bv   = (const float*)d_in[7];
    const float* pW1  = (const float*)d_in[8];
    const float* pb1  = (const float*)d_in[9];
    const float* pg1  = (const float*)d_in[10];
    const float* pbe1 = (const float*)d_in[11];
    const float* pW2  = (const float*)d_in[12];
    const float* pb2  = (const float*)d_in[13];
    const float* pg2  = (const float*)d_in[14];
    const float* pbe2 = (const float*)d_in[15];
    const float* aW1  = (const float*)d_in[16];
    const float* ab1  = (const float*)d_in[17];
    const float* ag1  = (const float*)d_in[18];
    const float* abe1 = (const float*)d_in[19];
    const float* aW2  = (const float*)d_in[20];
    const float* ab2  = (const float*)d_in[21];
    const float* ag2  = (const float*)d_in[22];
    const float* abe2 = (const float*)d_in[23];
    const int* fps_idx = (const int*)d_in[24];
    float* out = (float*)d_out;

    char* ws = (char*)d_ws;
    size_t off = 0;
    auto alloc = [&](size_t bytes) -> void* {
        void* r = ws + off;
        off = (off + bytes + 255) & ~(size_t)255;
        return r;
    };
    float* gacc  = (float*)alloc(160*68*4);          // zeroed
    float* stats = (float*)alloc(8*128*4);           // zeroed: 4 layers x (sum,sq)
    size_t zero_bytes = off;
    float* aff = (float*)alloc(8*128*4);             // 4 layers x (scale,shift)
    float* Cq  = (float*)alloc(128*64*4);
    float* Ck  = (float*)alloc(128*64*4);
    float* dq  = (float*)alloc(128*4);
    float* dk  = (float*)alloc(128*4);
    u16* Wb0   = (u16*)alloc(128*128*2);
    u16* Wb1   = (u16*)alloc(128*128*2);
    u16* Wb2   = (u16*)alloc(128*128*2);
    float* Aq2 = (float*)alloc((size_t)N_*128*4);
    float* Ak2 = (float*)alloc(160*128*4);
    float* xv  = (float*)alloc(160*128*4);
    u16* bigA  = (u16*)alloc((size_t)E_*128*2);      // z1 -> z2 (in place)
    u16* bigB  = (u16*)alloc((size_t)E_*128*2);      // za1 -> za2 (in place)

    hipMemsetAsync(d_ws, 0, zero_bytes, stream);

    prep_weights<<<68, 256, 0, stream>>>(Wq, bq, Wk, bk, aW1, ab1, pW2, aW2,
                                         Cq, Ck, dq, dk, Wb0, Wb1, Wb2);
    knn_scatter<<<64, 256, 0, stream>>>(pos, x, fps_idx, gacc);
    fps_finalize<<<160, 128, 0, stream>>>(gacc);
    proj_m<<<160, 128, 0, stream>>>(gacc, Ck, dk, Wv, bv, Ak2, xv);
    proj_q<<<N_/2, 256, 0, stream>>>(x, Cq, dq, Aq2);

    z1_stats<<<E_/256, 256, 0, stream>>>(pos, gacc, pW1, pb1, bigA, stats + 0);
    finalize_stats<<<1, 128, 0, stream>>>(stats + 0, pg1, pbe1, aff + 0, aff + 128);
    gemm_bn<<<E_/64, 256, 0, stream>>>(bigA, bigA, Wb0, aff + 0, aff + 128,
                                       pb2, nullptr, nullptr);            // -> z2
    stats_kernel<<<E_/256, 256, 0, stream>>>(bigA, stats + 256);
    finalize_stats<<<1, 128, 0, stream>>>(stats + 256, pg2, pbe2, aff + 256, aff + 384);
    gemm_bn<<<E_/64, 256, 0, stream>>>(bigA, bigB, Wb1, aff + 256, aff + 384,
                                       nullptr, Aq2, Ak2);                // -> za1
    stats_kernel<<<E_/256, 256, 0, stream>>>(bigB, stats + 512);
    finalize_stats<<<1, 128, 0, stream>>>(stats + 512, ag1, abe1, aff + 512, aff + 640);
    gemm_bn<<<E_/64, 256, 0, stream>>>(bigB, bigB, Wb2, aff + 512, aff + 640,
                                       ab2, nullptr, nullptr);            // -> za2
    stats_kernel<<<E_/256, 256, 0, stream>>>(bigB, stats + 768);
    finalize_stats<<<1, 128, 0, stream>>>(stats + 768, ag2, abe2, aff + 768, aff + 896);

    final_kernel<<<N_/2, 256, 0, stream>>>(bigA, bigB, aff + 256, aff + 384,
                                           aff + 768, aff + 896, xv, out);
}

// Round 2
// 528.697 us; speedup vs baseline: 1.4112x; 1.4112x over previous
//
#include <hip/hip_runtime.h>
#include <stdint.h>

#define B_ 8
#define P_ 2048
#define K_ 20
#define N_ (B_*P_)     // 16384
#define M_ (B_*K_)     // 160
#define C 128
#define E_ (N_*K_)     // 327680
#define EPS_ 1e-5f

typedef unsigned short u16;
typedef unsigned int u32;
typedef __attribute__((ext_vector_type(8))) short short8;
typedef __attribute__((ext_vector_type(4))) float floatx4;

__device__ __forceinline__ float bf2f(u16 u){
    union { u32 i; float f; } v; v.i = ((u32)u) << 16; return v.f;
}
__device__ __forceinline__ u16 f2bf(float f){
    union { float f; u32 i; } v; v.f = f;
    u32 r = ((v.i >> 16) & 1u) + 0x7fffu;
    return (u16)((v.i + r) >> 16);
}

// ---------------------------------------------------------------------------
// prep: Cq = aW1@Wq [128,64], Ck = aW1@Wk, dq = aW1@bq + ab1, dk = aW1@bk,
//       bf16 copies of pW2, aW1, aW2.  grid 68 x 256
__global__ __launch_bounds__(256)
void prep_weights(const float* __restrict__ Wq, const float* __restrict__ bq,
                  const float* __restrict__ Wk, const float* __restrict__ bk,
                  const float* __restrict__ aW1, const float* __restrict__ ab1,
                  const float* __restrict__ pW2, const float* __restrict__ aW2,
                  float* __restrict__ Cq, float* __restrict__ Ck,
                  float* __restrict__ dq, float* __restrict__ dk,
                  u16* __restrict__ Wb0, u16* __restrict__ Wb1, u16* __restrict__ Wb2)
{
    int tid = threadIdx.x, blk = blockIdx.x;
    if (blk < 32) {
        int idx = blk*256 + tid; int o = idx >> 6, i = idx & 63;
        float s = 0.f;
        for (int cc = 0; cc < 128; ++cc) s = fmaf(aW1[o*128+cc], Wq[cc*64+i], s);
        Cq[idx] = s;
    } else if (blk < 64) {
        int idx = (blk-32)*256 + tid; int o = idx >> 6, i = idx & 63;
        float s = 0.f;
        for (int cc = 0; cc < 128; ++cc) s = fmaf(aW1[o*128+cc], Wk[cc*64+i], s);
        Ck[idx] = s;
    } else if (blk == 64) {
        if (tid < 128) {
            float s = ab1[tid];
            for (int cc = 0; cc < 128; ++cc) s = fmaf(aW1[tid*128+cc], bq[cc], s);
            dq[tid] = s;
        } else {
            int o = tid - 128;
            float s = 0.f;
            for (int cc = 0; cc < 128; ++cc) s = fmaf(aW1[o*128+cc], bk[cc], s);
            dk[o] = s;
        }
    } else {
        const float* src = (blk == 65) ? pW2 : (blk == 66) ? aW1 : aW2;
        u16* dst = (blk == 65) ? Wb0 : (blk == 66) ? Wb1 : Wb2;
        for (int i = tid; i < 128*128; i += 256) dst[i] = f2bf(src[i]);
    }
}

// ---------------------------------------------------------------------------
// knn + kernel-weighted scatter into gacc[m][68] + per-graph pos moments.
// grid 64 x 256
__global__ __launch_bounds__(256)
void knn_scatter(const float* __restrict__ pos, const float* __restrict__ x,
                 const int* __restrict__ fps_idx, float* __restrict__ gacc,
                 float* __restrict__ posmom)
{
    __shared__ float fpos[K_][3];
    __shared__ float accL[K_][68];
    int tid = threadIdx.x;
    int b = blockIdx.x >> 3;              // 8 blocks per graph
    if (tid < K_*3) {
        int k = tid / 3, d = tid % 3;
        fpos[k][d] = pos[fps_idx[b*K_+k]*3 + d];
    }
    for (int i = tid; i < K_*68; i += 256) ((float*)accL)[i] = 0.f;
    __syncthreads();
    int p = blockIdx.x*256 + tid;
    float px = pos[p*3], py = pos[p*3+1], pz = pos[p*3+2];
    float best = 1e30f; int kb = 0;
    #pragma unroll
    for (int k = 0; k < K_; ++k) {
        float dx = px - fpos[k][0], dy = py - fpos[k][1], dz = pz - fpos[k][2];
        float d2 = dx*dx + dy*dy + dz*dz;
        if (d2 < best) { best = d2; kb = k; }
    }
    float ek = 1.0f / (1.0f + 5.0f*best);
    atomicAdd(&accL[kb][0], 1.0f);
    atomicAdd(&accL[kb][1], ek*px);
    atomicAdd(&accL[kb][2], ek*py);
    atomicAdd(&accL[kb][3], ek*pz);
    for (int cI = 0; cI < 64; ++cI) atomicAdd(&accL[kb][4+cI], ek*x[p*64+cI]);

    // per-graph moments of pos (wave reduce then one atomic per wave)
    float mom[9] = {px,py,pz, px*px,px*py,px*pz, py*py,py*pz, pz*pz};
    #pragma unroll
    for (int i = 0; i < 9; ++i) {
        float v = mom[i];
        v += __shfl_xor(v,32); v += __shfl_xor(v,16); v += __shfl_xor(v,8);
        v += __shfl_xor(v,4);  v += __shfl_xor(v,2);  v += __shfl_xor(v,1);
        mom[i] = v;
    }
    if ((tid & 63) == 0) {
        #pragma unroll
        for (int i = 0; i < 9; ++i) atomicAdd(&posmom[b*9+i], mom[i]);
    }
    __syncthreads();
    for (int i = tid; i < K_*68; i += 256) {
        int k = i / 68, f = i % 68;
        atomicAdd(&gacc[(b*K_+k)*68 + f], accL[k][f]);
    }
}

// divide sums by max(cnt,1) in place. grid 160 x 128
__global__ void fps_finalize(float* __restrict__ gacc)
{
    int m = blockIdx.x, t = threadIdx.x;
    float c = gacc[m*68]; c = c > 1.f ? c : 1.f;
    if (t >= 1 && t < 68) gacc[m*68+t] /= c;
}

// ---------------------------------------------------------------------------
// closed-form BN1 stats from rel moments; fold BN1+pW1 -> w3[4][128].
// single block x 256
__global__ __launch_bounds__(256)
void bn1_prep(const float* __restrict__ gacc, const float* __restrict__ posmom,
              const float* __restrict__ pW1, const float* __restrict__ pb1,
              const float* __restrict__ pg1, const float* __restrict__ pbe1,
              float* __restrict__ w3)
{
    __shared__ float sF[8][3], sG[8][6];
    __shared__ float S1[3], S2[6];
    int t = threadIdx.x;
    if (t < 8) {
        float F0=0,F1=0,F2=0,G0=0,G1=0,G2=0,G3=0,G4=0,G5=0;
        for (int k = 0; k < K_; ++k) {
            const float* f = gacc + (t*K_+k)*68 + 1;
            float x=f[0], y=f[1], z=f[2];
            F0+=x; F1+=y; F2+=z;
            G0+=x*x; G1+=x*y; G2+=x*z; G3+=y*y; G4+=y*z; G5+=z*z;
        }
        sF[t][0]=F0; sF[t][1]=F1; sF[t][2]=F2;
        sG[t][0]=G0; sG[t][1]=G1; sG[t][2]=G2; sG[t][3]=G3; sG[t][4]=G4; sG[t][5]=G5;
    }
    __syncthreads();
    if (t == 0) {
        float s1[3]={0,0,0}, s2[6]={0,0,0,0,0,0};
        for (int b = 0; b < 8; ++b) {
            const float* pm = posmom + b*9;
            float Ax=pm[0],Ay=pm[1],Az=pm[2];
            float Fx=sF[b][0],Fy=sF[b][1],Fz=sF[b][2];
            s1[0] += (float)K_*Ax - (float)P_*Fx;
            s1[1] += (float)K_*Ay - (float)P_*Fy;
            s1[2] += (float)K_*Az - (float)P_*Fz;
            s2[0] += (float)K_*pm[3] - 2.f*Ax*Fx + (float)P_*sG[b][0];
            s2[1] += (float)K_*pm[4] - Ax*Fy - Ay*Fx + (float)P_*sG[b][1];
            s2[2] += (float)K_*pm[5] - Ax*Fz - Az*Fx + (float)P_*sG[b][2];
            s2[3] += (float)K_*pm[6] - 2.f*Ay*Fy + (float)P_*sG[b][3];
            s2[4] += (float)K_*pm[7] - Ay*Fz - Az*Fy + (float)P_*sG[b][4];
            s2[5] += (float)K_*pm[8] - 2.f*Az*Fz + (float)P_*sG[b][5];
        }
        for (int i = 0; i < 3; ++i) S1[i] = s1[i];
        for (int i = 0; i < 6; ++i) S2[i] = s2[i];
    }
    __syncthreads();
    if (t < 128) {
        float w0=pW1[t*3], w1=pW1[t*3+1], w2=pW1[t*3+2], bb=pb1[t];
        float wS1 = w0*S1[0] + w1*S1[1] + w2*S1[2];
        float wS2w = w0*w0*S2[0] + w1*w1*S2[3] + w2*w2*S2[5]
                   + 2.f*(w0*w1*S2[1] + w0*w2*S2[2] + w1*w2*S2[4]);
        const float invE = 1.0f/(float)E_;
        float m1  = wS1*invE + bb;
        float Ez2 = (wS2w + 2.f*bb*wS1)*invE + bb*bb;
        float var = Ez2 - m1*m1;
        float sc = pg1[t] * rsqrtf(var + EPS_);
        float sh = pbe1[t] - m1*sc;
        w3[0*128+t] = w0*sc; w3[1*128+t] = w1*sc;
        w3[2*128+t] = w2*sc; w3[3*128+t] = bb*sc + sh;
    }
}

// Ak2[m] = Ck@fps_x + dk ; xv[m] = Wv@fps_x + bv. grid 160 x 128
__global__ __launch_bounds__(128)
void proj_m(const float* __restrict__ gacc, const float* __restrict__ Ck,
            const float* __restrict__ dk, const float* __restrict__ Wv,
            const float* __restrict__ bv, float* __restrict__ Ak2,
            float* __restrict__ xv)
{
    int m = blockIdx.x, o = threadIdx.x;
    const float* fx = gacc + m*68 + 4;
    float a = dk[o], v = bv[o];
    for (int i = 0; i < 64; ++i) {
        float xi = fx[i];
        a = fmaf(Ck[o*64+i], xi, a);
        v = fmaf(Wv[o*64+i], xi, v);
    }
    Ak2[m*C+o] = a; xv[m*C+o] = v;
}

// Aq2[p] = Cq@x[p] + dq. grid 8192 x 256 (2 points/block)
__global__ __launch_bounds__(256)
void proj_q(const float* __restrict__ x, const float* __restrict__ Cq,
            const float* __restrict__ dq, float* __restrict__ Aq2)
{
    __shared__ float xs[2][64];
    int tid = threadIdx.x;
    int p0 = blockIdx.x*2;
    if (tid < 128) xs[tid>>6][tid&63] = x[(p0 + (tid>>6))*64 + (tid&63)];
    __syncthreads();
    int pl = tid >> 7, o = tid & 127;
    float a = dq[o];
    const float* cq = Cq + o*64;
    const float* xr = xs[pl];
    #pragma unroll
    for (int i = 0; i < 64; i += 4) {
        a = fmaf(cq[i],   xr[i],   a);
        a = fmaf(cq[i+1], xr[i+1], a);
        a = fmaf(cq[i+2], xr[i+2], a);
        a = fmaf(cq[i+3], xr[i+3], a);
    }
    Aq2[(p0+pl)*C + o] = a;
}

// scale = g * rsqrt(var+eps); shift = be - mean*scale. 1 x 128
__global__ void finalize_stats(const float* __restrict__ sums,
                               const float* __restrict__ g, const float* __restrict__ be,
                               float* __restrict__ scale, float* __restrict__ shift)
{
    int c = threadIdx.x;
    if (c < C) {
        float mean = sums[c] * (1.0f/E_);
        float var  = sums[C+c] * (1.0f/E_) - mean*mean;
        float sc = g[c] * rsqrtf(var + EPS_);
        scale[c] = sc;
        shift[c] = be[c] - mean*sc;
    }
}

// ---------------------------------------------------------------------------
// Fused GEMM: out[e,:] = A(e,:) @ Wb^T (+bias) (+Aq2[p]-Ak2[m]), bf16 store,
// fused per-channel sum/sumsq of the fp32 outputs.
// MODE 0: A = relu(BN1-folded pos-MLP layer1) generated on the fly (gemm1)
// MODE 1: A = relu(zin*scale+shift); epilogue += Aq2[p]-Ak2[m]     (gemm2)
// MODE 2: A = relu(zin*scale+shift); epilogue += bias              (gemm3)
// 256 rows/block (4 waves x 4 tiles x 16 rows), B staged frag-major in LDS.
// grid 1280 x 256
template<int MODE>
__global__ __launch_bounds__(256, 3)
void gemm_fused(const u16* __restrict__ zin, u16* __restrict__ zout,
                const u16* __restrict__ Wb,
                const float* __restrict__ scale, const float* __restrict__ shift,
                const float* __restrict__ w3,
                const float* __restrict__ bias,
                const float* __restrict__ rowq, const float* __restrict__ rowk,
                const float* __restrict__ pos, const float* __restrict__ gacc,
                float* __restrict__ stats)
{
    __shared__ short8 sB[2048];                  // 32 KB, frag-major, conflict-free
    __shared__ short8 s_out_v[4][16][17];        // 17408 B, rows 16B-aligned
    __shared__ union {
        struct { float w[4][C]; float bias[C]; } m0;     // 2560 B
        struct { float sc[C]; float sh[C]; } m12;        // 1024 B
    } sU;
    __shared__ float s_bias2[C];                 // MODE 2 bias
    __shared__ float s_stat[2][C];               // fused stats accumulators

    int tid = threadIdx.x;
    const int wave = tid >> 6, lane = tid & 63;
    const int L = lane & 15, q = lane >> 4;

    // stage B into fragment-major LDS: slot s holds frag bytes for
    // (ct = s>>8, ks = (s>>6)&3, lane = s&63)
    for (int s = tid; s < 2048; s += 256) {
        int ln = s & 63, ks = (s >> 6) & 3, ct = s >> 8;
        int Ls = ln & 15, qs = ln >> 4;
        sB[s] = *(const short8*)(Wb + (ct*16+Ls)*C + ks*32 + qs*8);
    }
    if constexpr (MODE == 0) {
        for (int i = tid; i < 4*C; i += 256) ((float*)sU.m0.w)[i] = w3[i];
        if (tid < C) sU.m0.bias[tid] = bias[tid];
    } else {
        if (tid < C) { sU.m12.sc[tid] = scale[tid]; sU.m12.sh[tid] = shift[tid]; }
        if constexpr (MODE == 2) { if (tid < C) s_bias2[tid] = bias[tid]; }
    }
    ((float*)s_stat)[tid] = 0.f;
    __syncthreads();

    u16* s_out = (u16*)s_out_v;                  // [wave*16*136 + row*136 + col]
    const int rowbase = blockIdx.x*256 + wave*64;
    float ssum[8], ssq[8];
    #pragma unroll
    for (int i = 0; i < 8; ++i) { ssum[i] = 0.f; ssq[i] = 0.f; }

    short8 An[4];
    auto loadA = [&](int t) {
        const u16* ap = zin + (size_t)(rowbase + t*16 + L)*C + q*8;
        An[0] = *(const short8*)ap;
        An[1] = *(const short8*)(ap + 32);
        An[2] = *(const short8*)(ap + 64);
        An[3] = *(const short8*)(ap + 96);
    };
    if constexpr (MODE != 0) loadA(0);

    #pragma unroll
    for (int t = 0; t < 4; ++t) {
        const int tilebase = rowbase + t*16;
        floatx4 acc[8];
        #pragma unroll
        for (int ct = 0; ct < 8; ++ct) acc[ct] = (floatx4){0.f,0.f,0.f,0.f};

        short8 Ac[4];
        float r0, r1, r2;
        if constexpr (MODE != 0) {
            #pragma unroll
            for (int i = 0; i < 4; ++i) Ac[i] = An[i];
            if (t < 3) loadA(t+1);
        } else {
            // rel for this lane's row
            unsigned e = (unsigned)(tilebase + L);
            unsigned p = e / 20u; int k = (int)(e - p*20u);
            int m = (int)(p >> 11)*20 + k;
            const float* fp = gacc + m*68 + 1;
            r0 = pos[p*3]   - fp[0];
            r1 = pos[p*3+1] - fp[1];
            r2 = pos[p*3+2] - fp[2];
        }

        #pragma unroll
        for (int ks = 0; ks < 4; ++ks) {
            int ch0 = ks*32 + q*8;
            short8 af;
            if constexpr (MODE == 0) {
                floatx4 wx0 = *(const floatx4*)&sU.m0.w[0][ch0];
                floatx4 wx1 = *(const floatx4*)&sU.m0.w[0][ch0+4];
                floatx4 wy0 = *(const floatx4*)&sU.m0.w[1][ch0];
                floatx4 wy1 = *(const floatx4*)&sU.m0.w[1][ch0+4];
                floatx4 wz0 = *(const floatx4*)&sU.m0.w[2][ch0];
                floatx4 wz1 = *(const floatx4*)&sU.m0.w[2][ch0+4];
                floatx4 wb0 = *(const floatx4*)&sU.m0.w[3][ch0];
                floatx4 wb1 = *(const floatx4*)&sU.m0.w[3][ch0+4];
                #pragma unroll
                for (int j = 0; j < 4; ++j) {
                    float f = fmaf(wx0[j], r0, fmaf(wy0[j], r1, fmaf(wz0[j], r2, wb0[j])));
                    f = f > 0.f ? f : 0.f;
                    af[j] = (short)f2bf(f);
                }
                #pragma unroll
                for (int j = 0; j < 4; ++j) {
                    float f = fmaf(wx1[j], r0, fmaf(wy1[j], r1, fmaf(wz1[j], r2, wb1[j])));
                    f = f > 0.f ? f : 0.f;
                    af[4+j] = (short)f2bf(f);
                }
            } else {
                short8 ar = Ac[ks];
                floatx4 sc0 = *(const floatx4*)&sU.m12.sc[ch0];
                floatx4 sc1 = *(const floatx4*)&sU.m12.sc[ch0+4];
                floatx4 sh0 = *(const floatx4*)&sU.m12.sh[ch0];
                floatx4 sh1 = *(const floatx4*)&sU.m12.sh[ch0+4];
                #pragma unroll
                for (int j = 0; j < 4; ++j) {
                    float f = fmaf(bf2f((u16)ar[j]), sc0[j], sh0[j]);
                    f = f > 0.f ? f : 0.f;
                    af[j] = (short)f2bf(f);
                }
                #pragma unroll
                for (int j = 0; j < 4; ++j) {
                    float f = fmaf(bf2f((u16)ar[4+j]), sc1[j], sh1[j]);
                    f = f > 0.f ? f : 0.f;
                    af[4+j] = (short)f2bf(f);
                }
            }
            #pragma unroll
            for (int ct = 0; ct < 8; ++ct) {
                short8 bfr = sB[(ct*4+ks)*64 + lane];
                acc[ct] = __builtin_amdgcn_mfma_f32_16x16x32_bf16(af, bfr, acc[ct], 0, 0, 0);
            }
        }

        // epilogue
        int pp[4], mm[4];
        if constexpr (MODE == 1) {
            #pragma unroll
            for (int r = 0; r < 4; ++r) {
                unsigned e2 = (unsigned)(tilebase + q*4 + r);
                unsigned p2 = e2 / 20u; int k2 = (int)(e2 - p2*20u);
                pp[r] = (int)p2; mm[r] = (int)(p2 >> 11)*20 + k2;
            }
        }
        #pragma unroll
        for (int ct = 0; ct < 8; ++ct) {
            int col = ct*16 + L;
            float bb;
            if constexpr (MODE == 0) bb = sU.m0.bias[col];
            else if constexpr (MODE == 2) bb = s_bias2[col];
            else bb = 0.f;
            #pragma unroll
            for (int r = 0; r < 4; ++r) {
                float z = acc[ct][r] + bb;
                if constexpr (MODE == 1)
                    z += rowq[pp[r]*C + col] - rowk[mm[r]*C + col];
                ssum[ct] += z; ssq[ct] += z*z;
                s_out[wave*2176 + (q*4+r)*136 + col] = f2bf(z);
            }
        }
        // per-wave LDS ordering: all 64 lanes' ds_writes retire before reads
        asm volatile("s_waitcnt lgkmcnt(0)" ::: "memory");
        #pragma unroll
        for (int it = 0; it < 4; ++it) {
            int rr = it*4 + q;
            short8 v = *(const short8*)&s_out[wave*2176 + rr*136 + L*8];
            *(short8*)(zout + (size_t)(tilebase + rr)*C + L*8) = v;
        }
    }

    // fused stats: reduce over q via shuffles, LDS-accumulate, one global
    // atomic per channel per block
    #pragma unroll
    for (int ct = 0; ct < 8; ++ct) {
        float v = ssum[ct]; v += __shfl_xor(v,16); v += __shfl_xor(v,32);
        float w = ssq[ct];  w += __shfl_xor(w,16); w += __shfl_xor(w,32);
        if (q == 0) {
            atomicAdd(&s_stat[0][ct*16+L], v);
            atomicAdd(&s_stat[1][ct*16+L], w);
        }
    }
    __syncthreads();
    atomicAdd(&stats[tid], ((float*)s_stat)[tid]);
}

// ---------------------------------------------------------------------------
// final: alpha = softmax_k(relu(affine4(za2))); delta = relu(affine2(z2));
// out[p,c] = sum_k alpha * (xv[m,c] + delta). grid 8192 x 256
__global__ __launch_bounds__(256)
void final_kernel(const u16* __restrict__ z2, const u16* __restrict__ za2,
                  const float* __restrict__ sc2, const float* __restrict__ sh2,
                  const float* __restrict__ sc4, const float* __restrict__ sh4,
                  const float* __restrict__ xv, float* __restrict__ out)
{
    int tid = threadIdx.x;
    int p = blockIdx.x*2 + (tid >> 7);
    int c = tid & 127;
    int b = p >> 11;
    float S2 = sc2[c], H2 = sh2[c], S4 = sc4[c], H4 = sh4[c];
    float av[K_], dv[K_];
    size_t ebase = (size_t)p * K_;
    float mx = -1e30f;
    #pragma unroll
    for (int k = 0; k < K_; ++k) {
        size_t e = ebase + k;
        float a = fmaf(bf2f(za2[e*C + c]), S4, H4); a = a > 0.f ? a : 0.f;
        av[k] = a; if (a > mx) mx = a;
        float d = fmaf(bf2f(z2[e*C + c]), S2, H2); d = d > 0.f ? d : 0.f;
        dv[k] = d;
    }
    float ssum = 0.f;
    #pragma unroll
    for (int k = 0; k < K_; ++k) { av[k] = __expf(av[k] - mx); ssum += av[k]; }
    float inv = 1.0f / ssum;
    float o = 0.f;
    #pragma unroll
    for (int k = 0; k < K_; ++k) {
        float v = xv[(b*K_+k)*C + c] + dv[k];
        o = fmaf(av[k]*inv, v, o);
    }
    out[(size_t)p*C + c] = o;
}

// ---------------------------------------------------------------------------
extern "C" void kernel_launch(void* const* d_in, const int* in_sizes, int n_in,
                              void* d_out, int out_size, void* d_ws, size_t ws_size,
                              hipStream_t stream)
{
    const float* x    = (const float*)d_in[0];
    const float* pos  = (const float*)d_in[1];
    const float* Wq   = (const float*)d_in[2];
    const float* bq   = (const float*)d_in[3];
    const float* Wk   = (const float*)d_in[4];
    const float* bk   = (const float*)d_in[5];
    const float* Wv   = (const float*)d_in[6];
    const float* bv   = (const float*)d_in[7];
    const float* pW1  = (const float*)d_in[8];
    const float* pb1  = (const float*)d_in[9];
    const float* pg1  = (const float*)d_in[10];
    const float* pbe1 = (const float*)d_in[11];
    const float* pW2  = (const float*)d_in[12];
    const float* pb2  = (const float*)d_in[13];
    const float* pg2  = (const float*)d_in[14];
    const float* pbe2 = (const float*)d_in[15];
    const float* aW1  = (const float*)d_in[16];
    const float* ab1  = (const float*)d_in[17];
    const float* ag1  = (const float*)d_in[18];
    const float* abe1 = (const float*)d_in[19];
    const float* aW2  = (const float*)d_in[20];
    const float* ab2  = (const float*)d_in[21];
    const float* ag2  = (const float*)d_in[22];
    const float* abe2 = (const float*)d_in[23];
    const int* fps_idx = (const int*)d_in[24];
    float* out = (float*)d_out;

    char* ws = (char*)d_ws;
    size_t off = 0;
    auto alloc = [&](size_t bytes) -> void* {
        void* r = ws + off;
        off = (off + bytes + 255) & ~(size_t)255;
        return r;
    };
    float* gacc   = (float*)alloc(160*68*4);         // zeroed
    float* posmom = (float*)alloc(8*9*4);            // zeroed
    float* stats  = (float*)alloc(3*256*4);          // zeroed
    size_t zero_bytes = off;
    float* aff = (float*)alloc(6*128*4);             // sc2,sh2,sc3,sh3,sc4,sh4
    float* w3  = (float*)alloc(4*128*4);
    float* Cq  = (float*)alloc(128*64*4);
    float* Ck  = (float*)alloc(128*64*4);
    float* dq  = (float*)alloc(128*4);
    float* dk  = (float*)alloc(128*4);
    u16* Wb0   = (u16*)alloc(128*128*2);
    u16* Wb1   = (u16*)alloc(128*128*2);
    u16* Wb2   = (u16*)alloc(128*128*2);
    float* Aq2 = (float*)alloc((size_t)N_*128*4);
    float* Ak2 = (float*)alloc(160*128*4);
    float* xv  = (float*)alloc(160*128*4);
    u16* bigA  = (u16*)alloc((size_t)E_*128*2);      // z2
    u16* bigB  = (u16*)alloc((size_t)E_*128*2);      // za1 -> za2 (in place)

    hipMemsetAsync(d_ws, 0, zero_bytes, stream);

    prep_weights<<<68, 256, 0, stream>>>(Wq, bq, Wk, bk, aW1, ab1, pW2, aW2,
                                         Cq, Ck, dq, dk, Wb0, Wb1, Wb2);
    knn_scatter<<<64, 256, 0, stream>>>(pos, x, fps_idx, gacc, posmom);
    fps_finalize<<<160, 128, 0, stream>>>(gacc);
    bn1_prep<<<1, 256, 0, stream>>>(gacc, posmom, pW1, pb1, pg1, pbe1, w3);
    proj_m<<<160, 128, 0, stream>>>(gacc, Ck, dk, Wv, bv, Ak2, xv);
    proj_q<<<N_/2, 256, 0, stream>>>(x, Cq, dq, Aq2);

    // gemm1: rel -> z2 (bias pb2), stats of z2
    gemm_fused<0><<<E_/256, 256, 0, stream>>>(nullptr, bigA, Wb0,
        nullptr, nullptr, w3, pb2, nullptr, nullptr, pos, gacc, stats + 0);
    finalize_stats<<<1, 128, 0, stream>>>(stats + 0, pg2, pbe2, aff + 0, aff + 128);

    // gemm2: z2 -> za1 (+Aq2-Ak2), stats of za1
    gemm_fused<1><<<E_/256, 256, 0, stream>>>(bigA, bigB, Wb1,
        aff + 0, aff + 128, nullptr, nullptr, Aq2, Ak2, nullptr, nullptr, stats + 256);
    finalize_stats<<<1, 128, 0, stream>>>(stats + 256, ag1, abe1, aff + 256, aff + 384);

    // gemm3: za1 -> za2 (bias ab2), stats of za2
    gemm_fused<2><<<E_/256, 256, 0, stream>>>(bigB, bigB, Wb2,
        aff + 256, aff + 384, nullptr, ab2, nullptr, nullptr, nullptr, nullptr, stats + 512);
    finalize_stats<<<1, 128, 0, stream>>>(stats + 512, ag2, abe2, aff + 512, aff + 640);

    final_kernel<<<N_/2, 256, 0, stream>>>(bigA, bigB, aff + 0, aff + 128,
                                           aff + 512, aff + 640, xv, out);
}

// Round 3
// 427.017 us; speedup vs baseline: 1.7472x; 1.2381x over previous
//
#include <hip/hip_runtime.h>
#include <hip/hip_bf16.h>
#include <stdint.h>

#define B_ 8
#define P_ 2048
#define K_ 20
#define N_ (B_*P_)     // 16384
#define M_ (B_*K_)     // 160
#define C 128
#define E_ (N_*K_)     // 327680
#define EPS_ 1e-5f

typedef unsigned short u16;
typedef unsigned int u32;
typedef __attribute__((ext_vector_type(8))) short short8;
typedef __attribute__((ext_vector_type(4))) float floatx4;

__device__ __forceinline__ float bf2f(u16 u){
    union { u32 i; float f; } v; v.i = ((u32)u) << 16; return v.f;
}
__device__ __forceinline__ u16 f2bf(float f){
    union { float f; u32 i; } v; v.f = f;
    u32 r = ((v.i >> 16) & 1u) + 0x7fffu;
    return (u16)((v.i + r) >> 16);
}
__device__ __forceinline__ u32 pkbf(float a, float b){
    union { __hip_bfloat162 h; u32 u; } cv;
    cv.h = __float22bfloat162_rn(make_float2(a, b));
    return cv.u;
}

// ---------------------------------------------------------------------------
// prep: Cq = aW1@Wq [128,64], Ck = aW1@Wk, dq = aW1@bq + ab1, dk = aW1@bk,
//       frag-major bf16 copies of pW2, aW1, aW2 (MFMA B-operand layout).
// grid 68 x 256
__global__ __launch_bounds__(256)
void prep_weights(const float* __restrict__ Wq, const float* __restrict__ bq,
                  const float* __restrict__ Wk, const float* __restrict__ bk,
                  const float* __restrict__ aW1, const float* __restrict__ ab1,
                  const float* __restrict__ pW2, const float* __restrict__ aW2,
                  float* __restrict__ Cq, float* __restrict__ Ck,
                  float* __restrict__ dq, float* __restrict__ dk,
                  u16* __restrict__ Wb0, u16* __restrict__ Wb1, u16* __restrict__ Wb2)
{
    int tid = threadIdx.x, blk = blockIdx.x;
    if (blk < 32) {
        int idx = blk*256 + tid; int o = idx >> 6, i = idx & 63;
        float s = 0.f;
        for (int cc = 0; cc < 128; ++cc) s = fmaf(aW1[o*128+cc], Wq[cc*64+i], s);
        Cq[idx] = s;
    } else if (blk < 64) {
        int idx = (blk-32)*256 + tid; int o = idx >> 6, i = idx & 63;
        float s = 0.f;
        for (int cc = 0; cc < 128; ++cc) s = fmaf(aW1[o*128+cc], Wk[cc*64+i], s);
        Ck[idx] = s;
    } else if (blk == 64) {
        if (tid < 128) {
            float s = ab1[tid];
            for (int cc = 0; cc < 128; ++cc) s = fmaf(aW1[tid*128+cc], bq[cc], s);
            dq[tid] = s;
        } else {
            int o = tid - 128;
            float s = 0.f;
            for (int cc = 0; cc < 128; ++cc) s = fmaf(aW1[o*128+cc], bk[cc], s);
            dk[o] = s;
        }
    } else {
        // frag-major remap: slot s = (ct*4+ks)*64 + lane, 8 u16 per slot.
        // frag element j = W[ct*16 + (lane&15)][ks*32 + (lane>>4)*8 + j]
        const float* src = (blk == 65) ? pW2 : (blk == 66) ? aW1 : aW2;
        u16* dst = (blk == 65) ? Wb0 : (blk == 66) ? Wb1 : Wb2;
        for (int s = tid; s < 2048; s += 256) {
            int ln = s & 63, ks = (s >> 6) & 3, ct = s >> 8;
            int Ls = ln & 15, qs = ln >> 4;
            const float* sp = src + (ct*16+Ls)*C + ks*32 + qs*8;
            #pragma unroll
            for (int j = 0; j < 8; ++j) dst[s*8+j] = f2bf(sp[j]);
        }
    }
}

// ---------------------------------------------------------------------------
// knn + kernel-weighted scatter into gacc[m][68] + per-graph pos moments.
// grid 64 x 256
__global__ __launch_bounds__(256)
void knn_scatter(const float* __restrict__ pos, const float* __restrict__ x,
                 const int* __restrict__ fps_idx, float* __restrict__ gacc,
                 float* __restrict__ posmom)
{
    __shared__ float fpos[K_][3];
    __shared__ float accL[K_][68];
    int tid = threadIdx.x;
    int b = blockIdx.x >> 3;              // 8 blocks per graph
    if (tid < K_*3) {
        int k = tid / 3, d = tid % 3;
        fpos[k][d] = pos[fps_idx[b*K_+k]*3 + d];
    }
    for (int i = tid; i < K_*68; i += 256) ((float*)accL)[i] = 0.f;
    __syncthreads();
    int p = blockIdx.x*256 + tid;
    float px = pos[p*3], py = pos[p*3+1], pz = pos[p*3+2];
    float best = 1e30f; int kb = 0;
    #pragma unroll
    for (int k = 0; k < K_; ++k) {
        float dx = px - fpos[k][0], dy = py - fpos[k][1], dz = pz - fpos[k][2];
        float d2 = dx*dx + dy*dy + dz*dz;
        if (d2 < best) { best = d2; kb = k; }
    }
    float ek = 1.0f / (1.0f + 5.0f*best);
    atomicAdd(&accL[kb][0], 1.0f);
    atomicAdd(&accL[kb][1], ek*px);
    atomicAdd(&accL[kb][2], ek*py);
    atomicAdd(&accL[kb][3], ek*pz);
    for (int cI = 0; cI < 64; ++cI) atomicAdd(&accL[kb][4+cI], ek*x[p*64+cI]);

    float mom[9] = {px,py,pz, px*px,px*py,px*pz, py*py,py*pz, pz*pz};
    #pragma unroll
    for (int i = 0; i < 9; ++i) {
        float v = mom[i];
        v += __shfl_xor(v,32); v += __shfl_xor(v,16); v += __shfl_xor(v,8);
        v += __shfl_xor(v,4);  v += __shfl_xor(v,2);  v += __shfl_xor(v,1);
        mom[i] = v;
    }
    if ((tid & 63) == 0) {
        #pragma unroll
        for (int i = 0; i < 9; ++i) atomicAdd(&posmom[b*9+i], mom[i]);
    }
    __syncthreads();
    for (int i = tid; i < K_*68; i += 256) {
        int k = i / 68, f = i % 68;
        atomicAdd(&gacc[(b*K_+k)*68 + f], accL[k][f]);
    }
}

// divide sums by max(cnt,1) in place. grid 160 x 128
__global__ void fps_finalize(float* __restrict__ gacc)
{
    int m = blockIdx.x, t = threadIdx.x;
    float c = gacc[m*68]; c = c > 1.f ? c : 1.f;
    if (t >= 1 && t < 68) gacc[m*68+t] /= c;
}

// ---------------------------------------------------------------------------
// closed-form BN1 stats from rel moments; fold BN1+pW1 -> w3[4][128].
// single block x 256
__global__ __launch_bounds__(256)
void bn1_prep(const float* __restrict__ gacc, const float* __restrict__ posmom,
              const float* __restrict__ pW1, const float* __restrict__ pb1,
              const float* __restrict__ pg1, const float* __restrict__ pbe1,
              float* __restrict__ w3)
{
    __shared__ float sF[8][3], sG[8][6];
    __shared__ float S1[3], S2[6];
    int t = threadIdx.x;
    if (t < 8) {
        float F0=0,F1=0,F2=0,G0=0,G1=0,G2=0,G3=0,G4=0,G5=0;
        for (int k = 0; k < K_; ++k) {
            const float* f = gacc + (t*K_+k)*68 + 1;
            float x=f[0], y=f[1], z=f[2];
            F0+=x; F1+=y; F2+=z;
            G0+=x*x; G1+=x*y; G2+=x*z; G3+=y*y; G4+=y*z; G5+=z*z;
        }
        sF[t][0]=F0; sF[t][1]=F1; sF[t][2]=F2;
        sG[t][0]=G0; sG[t][1]=G1; sG[t][2]=G2; sG[t][3]=G3; sG[t][4]=G4; sG[t][5]=G5;
    }
    __syncthreads();
    if (t == 0) {
        float s1[3]={0,0,0}, s2[6]={0,0,0,0,0,0};
        for (int b = 0; b < 8; ++b) {
            const float* pm = posmom + b*9;
            float Ax=pm[0],Ay=pm[1],Az=pm[2];
            float Fx=sF[b][0],Fy=sF[b][1],Fz=sF[b][2];
            s1[0] += (float)K_*Ax - (float)P_*Fx;
            s1[1] += (float)K_*Ay - (float)P_*Fy;
            s1[2] += (float)K_*Az - (float)P_*Fz;
            s2[0] += (float)K_*pm[3] - 2.f*Ax*Fx + (float)P_*sG[b][0];
            s2[1] += (float)K_*pm[4] - Ax*Fy - Ay*Fx + (float)P_*sG[b][1];
            s2[2] += (float)K_*pm[5] - Ax*Fz - Az*Fx + (float)P_*sG[b][2];
            s2[3] += (float)K_*pm[6] - 2.f*Ay*Fy + (float)P_*sG[b][3];
            s2[4] += (float)K_*pm[7] - Ay*Fz - Az*Fy + (float)P_*sG[b][4];
            s2[5] += (float)K_*pm[8] - 2.f*Az*Fz + (float)P_*sG[b][5];
        }
        for (int i = 0; i < 3; ++i) S1[i] = s1[i];
        for (int i = 0; i < 6; ++i) S2[i] = s2[i];
    }
    __syncthreads();
    if (t < 128) {
        float w0=pW1[t*3], w1=pW1[t*3+1], w2=pW1[t*3+2], bb=pb1[t];
        float wS1 = w0*S1[0] + w1*S1[1] + w2*S1[2];
        float wS2w = w0*w0*S2[0] + w1*w1*S2[3] + w2*w2*S2[5]
                   + 2.f*(w0*w1*S2[1] + w0*w2*S2[2] + w1*w2*S2[4]);
        const float invE = 1.0f/(float)E_;
        float m1  = wS1*invE + bb;
        float Ez2 = (wS2w + 2.f*bb*wS1)*invE + bb*bb;
        float var = Ez2 - m1*m1;
        float sc = pg1[t] * rsqrtf(var + EPS_);
        float sh = pbe1[t] - m1*sc;
        w3[0*128+t] = w0*sc; w3[1*128+t] = w1*sc;
        w3[2*128+t] = w2*sc; w3[3*128+t] = bb*sc + sh;
    }
}

// Ak2[m] = Ck@fps_x + dk ; xv[m] = Wv@fps_x + bv. grid 160 x 128
__global__ __launch_bounds__(128)
void proj_m(const float* __restrict__ gacc, const float* __restrict__ Ck,
            const float* __restrict__ dk, const float* __restrict__ Wv,
            const float* __restrict__ bv, float* __restrict__ Ak2,
            float* __restrict__ xv)
{
    int m = blockIdx.x, o = threadIdx.x;
    const float* fx = gacc + m*68 + 4;
    float a = dk[o], v = bv[o];
    for (int i = 0; i < 64; ++i) {
        float xi = fx[i];
        a = fmaf(Ck[o*64+i], xi, a);
        v = fmaf(Wv[o*64+i], xi, v);
    }
    Ak2[m*C+o] = a; xv[m*C+o] = v;
}

// Aq2[p] = Cq@x[p] + dq. grid 8192 x 256 (2 points/block)
__global__ __launch_bounds__(256)
void proj_q(const float* __restrict__ x, const float* __restrict__ Cq,
            const float* __restrict__ dq, float* __restrict__ Aq2)
{
    __shared__ float xs[2][64];
    int tid = threadIdx.x;
    int p0 = blockIdx.x*2;
    if (tid < 128) xs[tid>>6][tid&63] = x[(p0 + (tid>>6))*64 + (tid&63)];
    __syncthreads();
    int pl = tid >> 7, o = tid & 127;
    float a = dq[o];
    const float* cq = Cq + o*64;
    const float* xr = xs[pl];
    #pragma unroll
    for (int i = 0; i < 64; i += 4) {
        a = fmaf(cq[i],   xr[i],   a);
        a = fmaf(cq[i+1], xr[i+1], a);
        a = fmaf(cq[i+2], xr[i+2], a);
        a = fmaf(cq[i+3], xr[i+3], a);
    }
    Aq2[(p0+pl)*C + o] = a;
}

// reduce 32 stat replicas, then scale = g*rsqrt(var+eps); shift = be - mean*sc.
// 1 block x 256
__global__ __launch_bounds__(256)
void finalize_stats(const float* __restrict__ stats32,
                    const float* __restrict__ g, const float* __restrict__ be,
                    float* __restrict__ scale, float* __restrict__ shift)
{
    __shared__ float red[256];
    int tid = threadIdx.x;
    float s = 0.f;
    for (int r = 0; r < 32; ++r) s += stats32[r*256 + tid];
    red[tid] = s;
    __syncthreads();
    if (tid < C) {
        float mean = red[tid] * (1.0f/E_);
        float var  = red[C+tid] * (1.0f/E_) - mean*mean;
        float sc = g[tid] * rsqrtf(var + EPS_);
        scale[tid] = sc;
        shift[tid] = be[tid] - mean*sc;
    }
}

// ---------------------------------------------------------------------------
// Fused GEMM v3: no big LDS, no hot-loop barriers. One 16-row tile per wave.
// out[e,:] = A(e,:) @ Wb^T (+bias) (+Aq2[p]-Ak2[m]); bf16 direct stores;
// fused per-channel sum/sumsq -> 32-way-replicated global stats.
// MODE 0: A = relu(BN1-folded pos-MLP layer1) on the fly
// MODE 1: A = relu(zin*sc+sh); epilogue += Aq2[p]-Ak2[m]
// MODE 2: A = relu(zin*sc+sh); epilogue += bias
// grid 5120 x 256 (4 waves x 16 rows = 64 rows/block)
template<int MODE>
__global__ __launch_bounds__(256, 3)
void gemm_fused(const u16* __restrict__ zin, u16* __restrict__ zout,
                const u16* __restrict__ Wbf,
                const float* __restrict__ scale, const float* __restrict__ shift,
                const float* __restrict__ w3,
                const float* __restrict__ bias,
                const float* __restrict__ rowq, const float* __restrict__ rowk,
                const float* __restrict__ pos, const float* __restrict__ gacc,
                float* __restrict__ stats32)
{
    __shared__ float s_stat[2][C];      // 1 KB
    __shared__ float saff[5*C];         // 2.5 KB affine params

    int tid = threadIdx.x;
    const int wave = tid >> 6, lane = tid & 63;
    const int L = lane & 15, q = lane >> 4;

    ((float*)s_stat)[tid] = 0.f;
    if constexpr (MODE == 0) {
        for (int i = tid; i < 512; i += 256) saff[i] = w3[i];
        if (tid < C) saff[512+tid] = bias[tid];
    } else {
        if (tid < C) { saff[tid] = scale[tid]; saff[C+tid] = shift[tid]; }
        if constexpr (MODE == 2) { if (tid < C) saff[2*C+tid] = bias[tid]; }
    }
    __syncthreads();

    const int tilebase = (blockIdx.x*4 + wave)*16;

    short8 An[4];
    float r0, r1, r2;
    if constexpr (MODE != 0) {
        const u16* ap = zin + (size_t)(tilebase + L)*C + q*8;
        An[0] = *(const short8*)ap;
        An[1] = *(const short8*)(ap + 32);
        An[2] = *(const short8*)(ap + 64);
        An[3] = *(const short8*)(ap + 96);
    } else {
        unsigned e = (unsigned)(tilebase + L);
        unsigned p = e / 20u; int k = (int)(e - p*20u);
        int m = (int)(p >> 11)*20 + k;
        const float* fp = gacc + m*68 + 1;
        r0 = pos[p*3]   - fp[0];
        r1 = pos[p*3+1] - fp[1];
        r2 = pos[p*3+2] - fp[2];
    }

    floatx4 acc[8];
    #pragma unroll
    for (int ct = 0; ct < 8; ++ct) acc[ct] = (floatx4){0.f,0.f,0.f,0.f};

    #pragma unroll
    for (int ks = 0; ks < 4; ++ks) {
        int ch0 = ks*32 + q*8;
        union { short8 s8; u32 u[4]; } af;
        if constexpr (MODE == 0) {
            #pragma unroll
            for (int jj = 0; jj < 4; ++jj) {
                int c0 = ch0 + jj*2, c1 = ch0 + jj*2 + 1;
                float f0 = fmaf(saff[c0], r0, fmaf(saff[C+c0], r1,
                           fmaf(saff[2*C+c0], r2, saff[3*C+c0])));
                float f1 = fmaf(saff[c1], r0, fmaf(saff[C+c1], r1,
                           fmaf(saff[2*C+c1], r2, saff[3*C+c1])));
                f0 = f0 > 0.f ? f0 : 0.f;
                f1 = f1 > 0.f ? f1 : 0.f;
                af.u[jj] = pkbf(f0, f1);
            }
        } else {
            short8 ar = An[ks];
            #pragma unroll
            for (int jj = 0; jj < 4; ++jj) {
                int c0 = ch0 + jj*2, c1 = ch0 + jj*2 + 1;
                float f0 = fmaf(bf2f((u16)ar[jj*2]),   saff[c0], saff[C+c0]);
                float f1 = fmaf(bf2f((u16)ar[jj*2+1]), saff[c1], saff[C+c1]);
                f0 = f0 > 0.f ? f0 : 0.f;
                f1 = f1 > 0.f ? f1 : 0.f;
                af.u[jj] = pkbf(f0, f1);
            }
        }
        #pragma unroll
        for (int ct = 0; ct < 8; ++ct) {
            short8 bfr = *(const short8*)(Wbf + ((ct*4+ks)*64 + lane)*8);
            acc[ct] = __builtin_amdgcn_mfma_f32_16x16x32_bf16(af.s8, bfr, acc[ct], 0, 0, 0);
        }
    }

    // epilogue: bias / qmk adds, fused stats, direct bf16 stores
    float ssum[8], ssq[8];
    #pragma unroll
    for (int i = 0; i < 8; ++i) { ssum[i] = 0.f; ssq[i] = 0.f; }

    int pp[4], mm[4];
    if constexpr (MODE == 1) {
        #pragma unroll
        for (int r = 0; r < 4; ++r) {
            unsigned e2 = (unsigned)(tilebase + q*4 + r);
            unsigned p2 = e2 / 20u; int k2 = (int)(e2 - p2*20u);
            pp[r] = (int)p2; mm[r] = (int)(p2 >> 11)*20 + k2;
        }
    }
    u16* orow = zout + (size_t)(tilebase + q*4)*C + L;
    #pragma unroll
    for (int ct = 0; ct < 8; ++ct) {
        int col = ct*16 + L;
        float bb;
        if constexpr (MODE == 0) bb = saff[4*C + col];
        else if constexpr (MODE == 2) bb = saff[2*C + col];
        else bb = 0.f;
        #pragma unroll
        for (int r = 0; r < 4; ++r) {
            float z = acc[ct][r] + bb;
            if constexpr (MODE == 1)
                z += rowq[pp[r]*C + col] - rowk[mm[r]*C + col];
            ssum[ct] += z; ssq[ct] += z*z;
            orow[(size_t)r*C + ct*16] = f2bf(z);
        }
    }

    // stats: reduce over q-groups via shuffles, LDS accumulate, one replica-
    // atomic burst per block
    #pragma unroll
    for (int ct = 0; ct < 8; ++ct) {
        float v = ssum[ct]; v += __shfl_xor(v,16); v += __shfl_xor(v,32);
        float w = ssq[ct];  w += __shfl_xor(w,16); w += __shfl_xor(w,32);
        if (lane < 16) {
            atomicAdd(&s_stat[0][ct*16+L], v);
            atomicAdd(&s_stat[1][ct*16+L], w);
        }
    }
    __syncthreads();
    float* dst = stats32 + ((blockIdx.x & 31) << 8);
    atomicAdd(&dst[tid], ((float*)s_stat)[tid]);
}

// ---------------------------------------------------------------------------
// final: alpha = softmax_k(relu(affine4(za2))); delta = relu(affine2(z2));
// out[p,c] = sum_k alpha*(xv[m,c]+delta). 2 channels/lane, 4 points/block.
// grid 4096 x 256
__global__ __launch_bounds__(256, 3)
void final_kernel(const u16* __restrict__ z2, const u16* __restrict__ za2,
                  const float* __restrict__ sc2, const float* __restrict__ sh2,
                  const float* __restrict__ sc4, const float* __restrict__ sh4,
                  const float* __restrict__ xv, float* __restrict__ out)
{
    int tid = threadIdx.x;
    int p = blockIdx.x*4 + (tid >> 6);
    int lane = tid & 63;
    int c2 = lane*2;
    int b = p >> 11;
    float S2x=sc2[c2], S2y=sc2[c2+1], H2x=sh2[c2], H2y=sh2[c2+1];
    float S4x=sc4[c2], S4y=sc4[c2+1], H4x=sh4[c2], H4y=sh4[c2+1];
    size_t ebase = (size_t)p * K_;
    const float* xvb = xv + (size_t)(b*K_)*C + c2;
    float a0[K_], a1[K_], v0[K_], v1[K_];
    float mx0 = -1e30f, mx1 = -1e30f;
    #pragma unroll
    for (int k = 0; k < K_; ++k) {
        u32 wa = *(const u32*)(za2 + (ebase+k)*C + c2);
        u32 wz = *(const u32*)(z2  + (ebase+k)*C + c2);
        float aa0 = fmaf(bf2f((u16)(wa & 0xffffu)), S4x, H4x); aa0 = aa0 > 0.f ? aa0 : 0.f;
        float aa1 = fmaf(bf2f((u16)(wa >> 16)),     S4y, H4y); aa1 = aa1 > 0.f ? aa1 : 0.f;
        float dd0 = fmaf(bf2f((u16)(wz & 0xffffu)), S2x, H2x); dd0 = dd0 > 0.f ? dd0 : 0.f;
        float dd1 = fmaf(bf2f((u16)(wz >> 16)),     S2y, H2y); dd1 = dd1 > 0.f ? dd1 : 0.f;
        float2 xvv = *(const float2*)(xvb + (size_t)k*C);
        a0[k] = aa0; a1[k] = aa1;
        v0[k] = xvv.x + dd0; v1[k] = xvv.y + dd1;
        mx0 = fmaxf(mx0, aa0); mx1 = fmaxf(mx1, aa1);
    }
    float l0 = 0.f, l1 = 0.f, o0 = 0.f, o1 = 0.f;
    #pragma unroll
    for (int k = 0; k < K_; ++k) {
        float e0 = __expf(a0[k] - mx0), e1 = __expf(a1[k] - mx1);
        l0 += e0; l1 += e1;
        o0 = fmaf(e0, v0[k], o0); o1 = fmaf(e1, v1[k], o1);
    }
    out[(size_t)p*C + c2]     = o0 / l0;
    out[(size_t)p*C + c2 + 1] = o1 / l1;
}

// ---------------------------------------------------------------------------
extern "C" void kernel_launch(void* const* d_in, const int* in_sizes, int n_in,
                              void* d_out, int out_size, void* d_ws, size_t ws_size,
                              hipStream_t stream)
{
    const float* x    = (const float*)d_in[0];
    const float* pos  = (const float*)d_in[1];
    const float* Wq   = (const float*)d_in[2];
    const float* bq   = (const float*)d_in[3];
    const float* Wk   = (const float*)d_in[4];
    const float* bk   = (const float*)d_in[5];
    const float* Wv   = (const float*)d_in[6];
    const float* bv   = (const float*)d_in[7];
    const float* pW1  = (const float*)d_in[8];
    const float* pb1  = (const float*)d_in[9];
    const float* pg1  = (const float*)d_in[10];
    const float* pbe1 = (const float*)d_in[11];
    const float* pW2  = (const float*)d_in[12];
    const float* pb2  = (const float*)d_in[13];
    const float* pg2  = (const float*)d_in[14];
    const float* pbe2 = (const float*)d_in[15];
    const float* aW1  = (const float*)d_in[16];
    const float* ab1  = (const float*)d_in[17];
    const float* ag1  = (const float*)d_in[18];
    const float* abe1 = (const float*)d_in[19];
    const float* aW2  = (const float*)d_in[20];
    const float* ab2  = (const float*)d_in[21];
    const float* ag2  = (const float*)d_in[22];
    const float* abe2 = (const float*)d_in[23];
    const int* fps_idx = (const int*)d_in[24];
    float* out = (float*)d_out;

    char* ws = (char*)d_ws;
    size_t off = 0;
    auto alloc = [&](size_t bytes) -> void* {
        void* r = ws + off;
        off = (off + bytes + 255) & ~(size_t)255;
        return r;
    };
    float* gacc    = (float*)alloc(160*68*4);        // zeroed
    float* posmom  = (float*)alloc(8*9*4);           // zeroed
    float* stats32 = (float*)alloc(3*32*256*4);      // zeroed (3 layers x 32 reps)
    size_t zero_bytes = off;
    float* aff = (float*)alloc(6*128*4);             // sc2,sh2,sc3,sh3,sc4,sh4
    float* w3  = (float*)alloc(4*128*4);
    float* Cq  = (float*)alloc(128*64*4);
    float* Ck  = (float*)alloc(128*64*4);
    float* dq  = (float*)alloc(128*4);
    float* dk  = (float*)alloc(128*4);
    u16* Wb0   = (u16*)alloc(128*128*2);             // frag-major
    u16* Wb1   = (u16*)alloc(128*128*2);
    u16* Wb2   = (u16*)alloc(128*128*2);
    float* Aq2 = (float*)alloc((size_t)N_*128*4);
    float* Ak2 = (float*)alloc(160*128*4);
    float* xv  = (float*)alloc(160*128*4);
    u16* bigA  = (u16*)alloc((size_t)E_*128*2);      // z2
    u16* bigB  = (u16*)alloc((size_t)E_*128*2);      // za1 -> za2 (in place)

    hipMemsetAsync(d_ws, 0, zero_bytes, stream);

    prep_weights<<<68, 256, 0, stream>>>(Wq, bq, Wk, bk, aW1, ab1, pW2, aW2,
                                         Cq, Ck, dq, dk, Wb0, Wb1, Wb2);
    knn_scatter<<<64, 256, 0, stream>>>(pos, x, fps_idx, gacc, posmom);
    fps_finalize<<<160, 128, 0, stream>>>(gacc);
    bn1_prep<<<1, 256, 0, stream>>>(gacc, posmom, pW1, pb1, pg1, pbe1, w3);
    proj_m<<<160, 128, 0, stream>>>(gacc, Ck, dk, Wv, bv, Ak2, xv);
    proj_q<<<N_/2, 256, 0, stream>>>(x, Cq, dq, Aq2);

    float* stA = stats32;
    float* stB = stats32 + 32*256;
    float* stC = stats32 + 2*32*256;

    // gemm1: rel -> z2 (bias pb2), stats of z2
    gemm_fused<0><<<E_/64, 256, 0, stream>>>(nullptr, bigA, Wb0,
        nullptr, nullptr, w3, pb2, nullptr, nullptr, pos, gacc, stA);
    finalize_stats<<<1, 256, 0, stream>>>(stA, pg2, pbe2, aff + 0, aff + 128);

    // gemm2: z2 -> za1 (+Aq2-Ak2), stats of za1
    gemm_fused<1><<<E_/64, 256, 0, stream>>>(bigA, bigB, Wb1,
        aff + 0, aff + 128, nullptr, nullptr, Aq2, Ak2, nullptr, nullptr, stB);
    finalize_stats<<<1, 256, 0, stream>>>(stB, ag1, abe1, aff + 256, aff + 384);

    // gemm3: za1 -> za2 (bias ab2), stats of za2
    gemm_fused<2><<<E_/64, 256, 0, stream>>>(bigB, bigB, Wb2,
        aff + 256, aff + 384, nullptr, ab2, nullptr, nullptr, nullptr, nullptr, stC);
    finalize_stats<<<1, 256, 0, stream>>>(stC, ag2, abe2, aff + 512, aff + 640);

    final_kernel<<<N_/4, 256, 0, stream>>>(bigA, bigB, aff + 0, aff + 128,
                                           aff + 512, aff + 640, xv, out);
}

// Round 4
// 387.372 us; speedup vs baseline: 1.9260x; 1.1023x over previous
//
#include <hip/hip_runtime.h>
#include <hip/hip_bf16.h>
#include <stdint.h>

#define B_ 8
#define P_ 2048
#define K_ 20
#define N_ (B_*P_)     // 16384
#define M_ (B_*K_)     // 160
#define C 128
#define E_ (N_*K_)     // 327680
#define EPS_ 1e-5f

typedef unsigned short u16;
typedef unsigned int u32;
typedef __attribute__((ext_vector_type(8))) short short8;
typedef __attribute__((ext_vector_type(4))) float floatx4;

__device__ __forceinline__ float bf2f(u16 u){
    union { u32 i; float f; } v; v.i = ((u32)u) << 16; return v.f;
}
__device__ __forceinline__ u16 f2bf(float f){
    union { float f; u32 i; } v; v.f = f;
    u32 r = ((v.i >> 16) & 1u) + 0x7fffu;
    return (u16)((v.i + r) >> 16);
}
__device__ __forceinline__ u32 pkbf(float a, float b){
    union { __hip_bfloat162 h; u32 u; } cv;
    cv.h = __float22bfloat162_rn(make_float2(a, b));
    return cv.u;
}

// ---------------------------------------------------------------------------
// prep: Cq = aW1@Wq [128,64], Ck = aW1@Wk, dq = aW1@bq + ab1, dk = aW1@bk,
//       frag-major bf16 copies of pW2, aW1, aW2 (MFMA B-operand layout).
// grid 68 x 256
__global__ __launch_bounds__(256)
void prep_weights(const float* __restrict__ Wq, const float* __restrict__ bq,
                  const float* __restrict__ Wk, const float* __restrict__ bk,
                  const float* __restrict__ aW1, const float* __restrict__ ab1,
                  const float* __restrict__ pW2, const float* __restrict__ aW2,
                  float* __restrict__ Cq, float* __restrict__ Ck,
                  float* __restrict__ dq, float* __restrict__ dk,
                  u16* __restrict__ Wb0, u16* __restrict__ Wb1, u16* __restrict__ Wb2)
{
    int tid = threadIdx.x, blk = blockIdx.x;
    if (blk < 32) {
        int idx = blk*256 + tid; int o = idx >> 6, i = idx & 63;
        float s = 0.f;
        for (int cc = 0; cc < 128; ++cc) s = fmaf(aW1[o*128+cc], Wq[cc*64+i], s);
        Cq[idx] = s;
    } else if (blk < 64) {
        int idx = (blk-32)*256 + tid; int o = idx >> 6, i = idx & 63;
        float s = 0.f;
        for (int cc = 0; cc < 128; ++cc) s = fmaf(aW1[o*128+cc], Wk[cc*64+i], s);
        Ck[idx] = s;
    } else if (blk == 64) {
        if (tid < 128) {
            float s = ab1[tid];
            for (int cc = 0; cc < 128; ++cc) s = fmaf(aW1[tid*128+cc], bq[cc], s);
            dq[tid] = s;
        } else {
            int o = tid - 128;
            float s = 0.f;
            for (int cc = 0; cc < 128; ++cc) s = fmaf(aW1[o*128+cc], bk[cc], s);
            dk[o] = s;
        }
    } else {
        // frag-major remap: slot s = (ct*4+ks)*64 + lane, 8 u16 per slot.
        // frag element j = W[ct*16 + (lane&15)][ks*32 + (lane>>4)*8 + j]
        const float* src = (blk == 65) ? pW2 : (blk == 66) ? aW1 : aW2;
        u16* dst = (blk == 65) ? Wb0 : (blk == 66) ? Wb1 : Wb2;
        for (int s = tid; s < 2048; s += 256) {
            int ln = s & 63, ks = (s >> 6) & 3, ct = s >> 8;
            int Ls = ln & 15, qs = ln >> 4;
            const float* sp = src + (ct*16+Ls)*C + ks*32 + qs*8;
            #pragma unroll
            for (int j = 0; j < 8; ++j) dst[s*8+j] = f2bf(sp[j]);
        }
    }
}

// ---------------------------------------------------------------------------
// knn + kernel-weighted scatter into gacc[m][68] + per-graph pos moments.
// One wave per block, 64 points per block; channel = lane (coalesced).
// grid 256 x 64
__global__ __launch_bounds__(64)
void knn_scatter(const float* __restrict__ pos, const float* __restrict__ x,
                 const int* __restrict__ fps_idx, float* __restrict__ gacc,
                 float* __restrict__ posmom)
{
    __shared__ float fpos[K_][3];
    __shared__ float accL[K_*68];
    int lane = threadIdx.x;
    int b = blockIdx.x >> 5;              // 32 blocks per graph
    if (lane < K_*3) {
        int k = lane / 3, d = lane - k*3;
        fpos[k][d] = pos[fps_idx[b*K_+k]*3 + d];
    }
    for (int i = lane; i < K_*68; i += 64) accL[i] = 0.f;
    __syncthreads();

    int wbase = blockIdx.x*64;
    int p = wbase + lane;
    float px = pos[p*3], py = pos[p*3+1], pz = pos[p*3+2];
    float best = 1e30f; int kb = 0;
    #pragma unroll
    for (int k = 0; k < K_; ++k) {
        float dx = px - fpos[k][0], dy = py - fpos[k][1], dz = pz - fpos[k][2];
        float d2 = dx*dx + dy*dy + dz*dz;
        if (d2 < best) { best = d2; kb = k; }   // strict <: keep first (argmin)
    }
    float ek = 1.0f / (1.0f + 5.0f*best);
    atomicAdd(&accL[kb*68 + 0], 1.0f);
    atomicAdd(&accL[kb*68 + 1], ek*px);
    atomicAdd(&accL[kb*68 + 2], ek*py);
    atomicAdd(&accL[kb*68 + 3], ek*pz);

    // per-graph moments of pos (wave reduce, one atomic burst)
    float mom[9] = {px,py,pz, px*px,px*py,px*pz, py*py,py*pz, pz*pz};
    #pragma unroll
    for (int i = 0; i < 9; ++i) {
        float v = mom[i];
        v += __shfl_xor(v,32); v += __shfl_xor(v,16); v += __shfl_xor(v,8);
        v += __shfl_xor(v,4);  v += __shfl_xor(v,2);  v += __shfl_xor(v,1);
        mom[i] = v;
    }
    if (lane == 0) {
        #pragma unroll
        for (int i = 0; i < 9; ++i) atomicAdd(&posmom[b*9+i], mom[i]);
    }

    // x scatter: broadcast (kb, ek) of point j; lane = channel (coalesced read,
    // conflict-free LDS atomic: 64 consecutive floats = 2-way alias = free)
    for (int j = 0; j < 64; ++j) {
        int   kbj = __shfl(kb, j);
        float ekj = __shfl(ek, j);
        float xv = x[(size_t)(wbase+j)*64 + lane];
        atomicAdd(&accL[kbj*68 + 4 + lane], ekj*xv);
    }
    __syncthreads();
    // flush: gacc flat layout matches accL flat layout per graph
    for (int i = lane; i < K_*68; i += 64)
        atomicAdd(&gacc[b*K_*68 + i], accL[i]);
}

// divide sums by max(cnt,1) in place. grid 160 x 128
__global__ void fps_finalize(float* __restrict__ gacc)
{
    int m = blockIdx.x, t = threadIdx.x;
    float c = gacc[m*68]; c = c > 1.f ? c : 1.f;
    if (t >= 1 && t < 68) gacc[m*68+t] /= c;
}

// ---------------------------------------------------------------------------
// closed-form BN1 stats from rel moments; fold BN1+pW1 -> w3[4][128].
// single block x 256
__global__ __launch_bounds__(256)
void bn1_prep(const float* __restrict__ gacc, const float* __restrict__ posmom,
              const float* __restrict__ pW1, const float* __restrict__ pb1,
              const float* __restrict__ pg1, const float* __restrict__ pbe1,
              float* __restrict__ w3)
{
    __shared__ float sF[8][3], sG[8][6];
    __shared__ float S1[3], S2[6];
    int t = threadIdx.x;
    if (t < 8) {
        float F0=0,F1=0,F2=0,G0=0,G1=0,G2=0,G3=0,G4=0,G5=0;
        for (int k = 0; k < K_; ++k) {
            const float* f = gacc + (t*K_+k)*68 + 1;
            float x=f[0], y=f[1], z=f[2];
            F0+=x; F1+=y; F2+=z;
            G0+=x*x; G1+=x*y; G2+=x*z; G3+=y*y; G4+=y*z; G5+=z*z;
        }
        sF[t][0]=F0; sF[t][1]=F1; sF[t][2]=F2;
        sG[t][0]=G0; sG[t][1]=G1; sG[t][2]=G2; sG[t][3]=G3; sG[t][4]=G4; sG[t][5]=G5;
    }
    __syncthreads();
    if (t == 0) {
        float s1[3]={0,0,0}, s2[6]={0,0,0,0,0,0};
        for (int b = 0; b < 8; ++b) {
            const float* pm = posmom + b*9;
            float Ax=pm[0],Ay=pm[1],Az=pm[2];
            float Fx=sF[b][0],Fy=sF[b][1],Fz=sF[b][2];
            s1[0] += (float)K_*Ax - (float)P_*Fx;
            s1[1] += (float)K_*Ay - (float)P_*Fy;
            s1[2] += (float)K_*Az - (float)P_*Fz;
            s2[0] += (float)K_*pm[3] - 2.f*Ax*Fx + (float)P_*sG[b][0];
            s2[1] += (float)K_*pm[4] - Ax*Fy - Ay*Fx + (float)P_*sG[b][1];
            s2[2] += (float)K_*pm[5] - Ax*Fz - Az*Fx + (float)P_*sG[b][2];
            s2[3] += (float)K_*pm[6] - 2.f*Ay*Fy + (float)P_*sG[b][3];
            s2[4] += (float)K_*pm[7] - Ay*Fz - Az*Fy + (float)P_*sG[b][4];
            s2[5] += (float)K_*pm[8] - 2.f*Az*Fz + (float)P_*sG[b][5];
        }
        for (int i = 0; i < 3; ++i) S1[i] = s1[i];
        for (int i = 0; i < 6; ++i) S2[i] = s2[i];
    }
    __syncthreads();
    if (t < 128) {
        float w0=pW1[t*3], w1=pW1[t*3+1], w2=pW1[t*3+2], bb=pb1[t];
        float wS1 = w0*S1[0] + w1*S1[1] + w2*S1[2];
        float wS2w = w0*w0*S2[0] + w1*w1*S2[3] + w2*w2*S2[5]
                   + 2.f*(w0*w1*S2[1] + w0*w2*S2[2] + w1*w2*S2[4]);
        const float invE = 1.0f/(float)E_;
        float m1  = wS1*invE + bb;
        float Ez2 = (wS2w + 2.f*bb*wS1)*invE + bb*bb;
        float var = Ez2 - m1*m1;
        float sc = pg1[t] * rsqrtf(var + EPS_);
        float sh = pbe1[t] - m1*sc;
        w3[0*128+t] = w0*sc; w3[1*128+t] = w1*sc;
        w3[2*128+t] = w2*sc; w3[3*128+t] = bb*sc + sh;
    }
}

// Ak2[m] = Ck@fps_x + dk ; xv[m] = Wv@fps_x + bv. grid 160 x 128
__global__ __launch_bounds__(128)
void proj_m(const float* __restrict__ gacc, const float* __restrict__ Ck,
            const float* __restrict__ dk, const float* __restrict__ Wv,
            const float* __restrict__ bv, float* __restrict__ Ak2,
            float* __restrict__ xv)
{
    int m = blockIdx.x, o = threadIdx.x;
    const float* fx = gacc + m*68 + 4;
    float a = dk[o], v = bv[o];
    for (int i = 0; i < 64; ++i) {
        float xi = fx[i];
        a = fmaf(Ck[o*64+i], xi, a);
        v = fmaf(Wv[o*64+i], xi, v);
    }
    Ak2[m*C+o] = a; xv[m*C+o] = v;
}

// Aq2[p] = Cq@x[p] + dq. grid 8192 x 256 (2 points/block)
__global__ __launch_bounds__(256)
void proj_q(const float* __restrict__ x, const float* __restrict__ Cq,
            const float* __restrict__ dq, float* __restrict__ Aq2)
{
    __shared__ float xs[2][64];
    int tid = threadIdx.x;
    int p0 = blockIdx.x*2;
    if (tid < 128) xs[tid>>6][tid&63] = x[(p0 + (tid>>6))*64 + (tid&63)];
    __syncthreads();
    int pl = tid >> 7, o = tid & 127;
    float a = dq[o];
    const float* cq = Cq + o*64;
    const float* xr = xs[pl];
    #pragma unroll
    for (int i = 0; i < 64; i += 4) {
        a = fmaf(cq[i],   xr[i],   a);
        a = fmaf(cq[i+1], xr[i+1], a);
        a = fmaf(cq[i+2], xr[i+2], a);
        a = fmaf(cq[i+3], xr[i+3], a);
    }
    Aq2[(p0+pl)*C + o] = a;
}

// reduce 32 stat replicas, then scale = g*rsqrt(var+eps); shift = be - mean*sc.
// 1 block x 256
__global__ __launch_bounds__(256)
void finalize_stats(const float* __restrict__ stats32,
                    const float* __restrict__ g, const float* __restrict__ be,
                    float* __restrict__ scale, float* __restrict__ shift)
{
    __shared__ float red[256];
    int tid = threadIdx.x;
    float s = 0.f;
    for (int r = 0; r < 32; ++r) s += stats32[r*256 + tid];
    red[tid] = s;
    __syncthreads();
    if (tid < C) {
        float mean = red[tid] * (1.0f/E_);
        float var  = red[C+tid] * (1.0f/E_) - mean*mean;
        float sc = g[tid] * rsqrtf(var + EPS_);
        scale[tid] = sc;
        shift[tid] = be[tid] - mean*sc;
    }
}

// ---------------------------------------------------------------------------
// Fused GEMM v4: two 16-row tiles per wave (ILP), B-frags loaded once per ks
// and shared by both tiles; no block barrier in the hot path.
// out[e,:] = A(e,:) @ Wb^T (+bias) (+Aq2[p]-Ak2[m]); bf16 direct stores;
// fused per-channel sum/sumsq -> 32-way-replicated global stats.
// MODE 0: A = relu(BN1-folded pos-MLP layer1) on the fly
// MODE 1: A = relu(zin*sc+sh); epilogue += Aq2[p]-Ak2[m]
// MODE 2: A = relu(zin*sc+sh); epilogue += bias
// grid 2560 x 256 (4 waves x 2 tiles x 16 rows = 128 rows/block)
template<int MODE>
__global__ __launch_bounds__(256)
void gemm_fused(const u16* __restrict__ zin, u16* __restrict__ zout,
                const u16* __restrict__ Wbf,
                const float* __restrict__ scale, const float* __restrict__ shift,
                const float* __restrict__ w3,
                const float* __restrict__ bias,
                const float* __restrict__ rowq, const float* __restrict__ rowk,
                const float* __restrict__ pos, const float* __restrict__ gacc,
                float* __restrict__ stats32)
{
    __shared__ float s_stat[2][C];      // 1 KB
    __shared__ float saff[5*C];         // 2.5 KB affine params

    int tid = threadIdx.x;
    const int wave = tid >> 6, lane = tid & 63;
    const int L = lane & 15, q = lane >> 4;

    ((float*)s_stat)[tid] = 0.f;
    if constexpr (MODE == 0) {
        for (int i = tid; i < 512; i += 256) saff[i] = w3[i];
        if (tid < C) saff[512+tid] = bias[tid];
    } else {
        if (tid < C) { saff[tid] = scale[tid]; saff[C+tid] = shift[tid]; }
        if constexpr (MODE == 2) { if (tid < C) saff[2*C+tid] = bias[tid]; }
    }
    __syncthreads();

    int tbs[2];
    tbs[0] = (blockIdx.x*8 + wave)*16;
    tbs[1] = (blockIdx.x*8 + wave + 4)*16;

    short8 An[2][4];
    float rr0[2], rr1[2], rr2[2];
    #pragma unroll
    for (int tt = 0; tt < 2; ++tt) {
        if constexpr (MODE != 0) {
            const u16* ap = zin + (size_t)(tbs[tt] + L)*C + q*8;
            An[tt][0] = *(const short8*)ap;
            An[tt][1] = *(const short8*)(ap + 32);
            An[tt][2] = *(const short8*)(ap + 64);
            An[tt][3] = *(const short8*)(ap + 96);
        } else {
            unsigned e = (unsigned)(tbs[tt] + L);
            unsigned p = e / 20u; int k = (int)(e - p*20u);
            int m = (int)(p >> 11)*20 + k;
            const float* fp = gacc + m*68 + 1;
            rr0[tt] = pos[p*3]   - fp[0];
            rr1[tt] = pos[p*3+1] - fp[1];
            rr2[tt] = pos[p*3+2] - fp[2];
        }
    }

    floatx4 acc[2][8];
    #pragma unroll
    for (int tt = 0; tt < 2; ++tt)
        #pragma unroll
        for (int ct = 0; ct < 8; ++ct) acc[tt][ct] = (floatx4){0.f,0.f,0.f,0.f};

    #pragma unroll
    for (int ks = 0; ks < 4; ++ks) {
        int ch0 = ks*32 + q*8;
        short8 bfr[8];
        #pragma unroll
        for (int ct = 0; ct < 8; ++ct)
            bfr[ct] = *(const short8*)(Wbf + ((ct*4+ks)*64 + lane)*8);
        #pragma unroll
        for (int tt = 0; tt < 2; ++tt) {
            union { short8 s8; u32 u[4]; } af;
            if constexpr (MODE == 0) {
                #pragma unroll
                for (int jj = 0; jj < 4; ++jj) {
                    int c0 = ch0 + jj*2, c1 = ch0 + jj*2 + 1;
                    float f0 = fmaf(saff[c0], rr0[tt], fmaf(saff[C+c0], rr1[tt],
                               fmaf(saff[2*C+c0], rr2[tt], saff[3*C+c0])));
                    float f1 = fmaf(saff[c1], rr0[tt], fmaf(saff[C+c1], rr1[tt],
                               fmaf(saff[2*C+c1], rr2[tt], saff[3*C+c1])));
                    f0 = f0 > 0.f ? f0 : 0.f;
                    f1 = f1 > 0.f ? f1 : 0.f;
                    af.u[jj] = pkbf(f0, f1);
                }
            } else {
                short8 ar = An[tt][ks];
                #pragma unroll
                for (int jj = 0; jj < 4; ++jj) {
                    int c0 = ch0 + jj*2, c1 = ch0 + jj*2 + 1;
                    float f0 = fmaf(bf2f((u16)ar[jj*2]),   saff[c0], saff[C+c0]);
                    float f1 = fmaf(bf2f((u16)ar[jj*2+1]), saff[c1], saff[C+c1]);
                    f0 = f0 > 0.f ? f0 : 0.f;
                    f1 = f1 > 0.f ? f1 : 0.f;
                    af.u[jj] = pkbf(f0, f1);
                }
            }
            #pragma unroll
            for (int ct = 0; ct < 8; ++ct)
                acc[tt][ct] = __builtin_amdgcn_mfma_f32_16x16x32_bf16(af.s8, bfr[ct], acc[tt][ct], 0, 0, 0);
        }
    }

    // epilogue: bias / qmk adds, fused stats, direct bf16 stores
    float ssum[8], ssq[8];
    #pragma unroll
    for (int i = 0; i < 8; ++i) { ssum[i] = 0.f; ssq[i] = 0.f; }

    #pragma unroll
    for (int tt = 0; tt < 2; ++tt) {
        const int tilebase = tbs[tt];
        int pp[4], mm[4];
        if constexpr (MODE == 1) {
            #pragma unroll
            for (int r = 0; r < 4; ++r) {
                unsigned e2 = (unsigned)(tilebase + q*4 + r);
                unsigned p2 = e2 / 20u; int k2 = (int)(e2 - p2*20u);
                pp[r] = (int)p2; mm[r] = (int)(p2 >> 11)*20 + k2;
            }
        }
        u16* orow = zout + (size_t)(tilebase + q*4)*C + L;
        #pragma unroll
        for (int ct = 0; ct < 8; ++ct) {
            int col = ct*16 + L;
            float bb;
            if constexpr (MODE == 0) bb = saff[4*C + col];
            else if constexpr (MODE == 2) bb = saff[2*C + col];
            else bb = 0.f;
            #pragma unroll
            for (int r = 0; r < 4; ++r) {
                float z = acc[tt][ct][r] + bb;
                if constexpr (MODE == 1)
                    z += rowq[pp[r]*C + col] - rowk[mm[r]*C + col];
                ssum[ct] += z; ssq[ct] += z*z;
                orow[(size_t)r*C + ct*16] = (u16)pkbf(z, z);
            }
        }
    }

    // stats: reduce over q-groups via shuffles, LDS accumulate, one replica-
    // atomic burst per block
    #pragma unroll
    for (int ct = 0; ct < 8; ++ct) {
        float v = ssum[ct]; v += __shfl_xor(v,16); v += __shfl_xor(v,32);
        float w = ssq[ct];  w += __shfl_xor(w,16); w += __shfl_xor(w,32);
        if (lane < 16) {
            atomicAdd(&s_stat[0][ct*16+L], v);
            atomicAdd(&s_stat[1][ct*16+L], w);
        }
    }
    __syncthreads();
    float* dst = stats32 + ((blockIdx.x & 31) << 8);
    atomicAdd(&dst[tid], ((float*)s_stat)[tid]);
}

// ---------------------------------------------------------------------------
// final: alpha = softmax_k(relu(affine4(za2))); delta = relu(affine2(z2));
// out[p,c] = sum_k alpha*(xv[m,c]+delta). Online (max-free: relu(BN'd) values
// are O(1), exp safe in fp32). 2 channels/lane, 4 points/block. grid 4096x256
__global__ __launch_bounds__(256)
void final_kernel(const u16* __restrict__ z2, const u16* __restrict__ za2,
                  const float* __restrict__ sc2, const float* __restrict__ sh2,
                  const float* __restrict__ sc4, const float* __restrict__ sh4,
                  const float* __restrict__ xv, float* __restrict__ out)
{
    int tid = threadIdx.x;
    int p = blockIdx.x*4 + (tid >> 6);
    int lane = tid & 63;
    int c2 = lane*2;
    int b = p >> 11;
    float S2x=sc2[c2], S2y=sc2[c2+1], H2x=sh2[c2], H2y=sh2[c2+1];
    float S4x=sc4[c2], S4y=sc4[c2+1], H4x=sh4[c2], H4y=sh4[c2+1];
    size_t ebase = (size_t)p * K_;
    const float* xvb = xv + (size_t)(b*K_)*C + c2;
    float l0 = 0.f, l1 = 0.f, o0 = 0.f, o1 = 0.f;
    #pragma unroll
    for (int k = 0; k < K_; ++k) {
        u32 wa = *(const u32*)(za2 + (ebase+k)*C + c2);
        u32 wz = *(const u32*)(z2  + (ebase+k)*C + c2);
        float2 xvv = *(const float2*)(xvb + (size_t)k*C);
        float aa0 = fmaf(bf2f((u16)(wa & 0xffffu)), S4x, H4x); aa0 = aa0 > 0.f ? aa0 : 0.f;
        float aa1 = fmaf(bf2f((u16)(wa >> 16)),     S4y, H4y); aa1 = aa1 > 0.f ? aa1 : 0.f;
        float dd0 = fmaf(bf2f((u16)(wz & 0xffffu)), S2x, H2x); dd0 = dd0 > 0.f ? dd0 : 0.f;
        float dd1 = fmaf(bf2f((u16)(wz >> 16)),     S2y, H2y); dd1 = dd1 > 0.f ? dd1 : 0.f;
        float e0 = __expf(aa0), e1 = __expf(aa1);
        l0 += e0; l1 += e1;
        o0 = fmaf(e0, xvv.x + dd0, o0);
        o1 = fmaf(e1, xvv.y + dd1, o1);
    }
    out[(size_t)p*C + c2]     = o0 / l0;
    out[(size_t)p*C + c2 + 1] = o1 / l1;
}

// ---------------------------------------------------------------------------
extern "C" void kernel_launch(void* const* d_in, const int* in_sizes, int n_in,
                              void* d_out, int out_size, void* d_ws, size_t ws_size,
                              hipStream_t stream)
{
    const float* x    = (const float*)d_in[0];
    const float* pos  = (const float*)d_in[1];
    const float* Wq   = (const float*)d_in[2];
    const float* bq   = (const float*)d_in[3];
    const float* Wk   = (const float*)d_in[4];
    const float* bk   = (const float*)d_in[5];
    const float* Wv   = (const float*)d_in[6];
    const float* bv   = (const float*)d_in[7];
    const float* pW1  = (const float*)d_in[8];
    const float* pb1  = (const float*)d_in[9];
    const float* pg1  = (const float*)d_in[10];
    const float* pbe1 = (const float*)d_in[11];
    const float* pW2  = (const float*)d_in[12];
    const float* pb2  = (const float*)d_in[13];
    const float* pg2  = (const float*)d_in[14];
    const float* pbe2 = (const float*)d_in[15];
    const float* aW1  = (const float*)d_in[16];
    const float* ab1  = (const float*)d_in[17];
    const float* ag1  = (const float*)d_in[18];
    const float* abe1 = (const float*)d_in[19];
    const float* aW2  = (const float*)d_in[20];
    const float* ab2  = (const float*)d_in[21];
    const float* ag2  = (const float*)d_in[22];
    const float* abe2 = (const float*)d_in[23];
    const int* fps_idx = (const int*)d_in[24];
    float* out = (float*)d_out;

    char* ws = (char*)d_ws;
    size_t off = 0;
    auto alloc = [&](size_t bytes) -> void* {
        void* r = ws + off;
        off = (off + bytes + 255) & ~(size_t)255;
        return r;
    };
    float* gacc    = (float*)alloc(160*68*4);        // zeroed
    float* posmom  = (float*)alloc(8*9*4);           // zeroed
    float* stats32 = (float*)alloc(3*32*256*4);      // zeroed (3 layers x 32 reps)
    size_t zero_bytes = off;
    float* aff = (float*)alloc(6*128*4);             // sc2,sh2,sc3,sh3,sc4,sh4
    float* w3  = (float*)alloc(4*128*4);
    float* Cq  = (float*)alloc(128*64*4);
    float* Ck  = (float*)alloc(128*64*4);
    float* dq  = (float*)alloc(128*4);
    float* dk  = (float*)alloc(128*4);
    u16* Wb0   = (u16*)alloc(128*128*2);             // frag-major
    u16* Wb1   = (u16*)alloc(128*128*2);
    u16* Wb2   = (u16*)alloc(128*128*2);
    float* Aq2 = (float*)alloc((size_t)N_*128*4);
    float* Ak2 = (float*)alloc(160*128*4);
    float* xv  = (float*)alloc(160*128*4);
    u16* bigA  = (u16*)alloc((size_t)E_*128*2);      // z2
    u16* bigB  = (u16*)alloc((size_t)E_*128*2);      // za1 -> za2 (in place)

    hipMemsetAsync(d_ws, 0, zero_bytes, stream);

    prep_weights<<<68, 256, 0, stream>>>(Wq, bq, Wk, bk, aW1, ab1, pW2, aW2,
                                         Cq, Ck, dq, dk, Wb0, Wb1, Wb2);
    knn_scatter<<<256, 64, 0, stream>>>(pos, x, fps_idx, gacc, posmom);
    fps_finalize<<<160, 128, 0, stream>>>(gacc);
    bn1_prep<<<1, 256, 0, stream>>>(gacc, posmom, pW1, pb1, pg1, pbe1, w3);
    proj_m<<<160, 128, 0, stream>>>(gacc, Ck, dk, Wv, bv, Ak2, xv);
    proj_q<<<N_/2, 256, 0, stream>>>(x, Cq, dq, Aq2);

    float* stA = stats32;
    float* stB = stats32 + 32*256;
    float* stC = stats32 + 2*32*256;

    // gemm1: rel -> z2 (bias pb2), stats of z2
    gemm_fused<0><<<E_/128, 256, 0, stream>>>(nullptr, bigA, Wb0,
        nullptr, nullptr, w3, pb2, nullptr, nullptr, pos, gacc, stA);
    finalize_stats<<<1, 256, 0, stream>>>(stA, pg2, pbe2, aff + 0, aff + 128);

    // gemm2: z2 -> za1 (+Aq2-Ak2), stats of za1
    gemm_fused<1><<<E_/128, 256, 0, stream>>>(bigA, bigB, Wb1,
        aff + 0, aff + 128, nullptr, nullptr, Aq2, Ak2, nullptr, nullptr, stB);
    finalize_stats<<<1, 256, 0, stream>>>(stB, ag1, abe1, aff + 256, aff + 384);

    // gemm3: za1 -> za2 (bias ab2), stats of za2
    gemm_fused<2><<<E_/128, 256, 0, stream>>>(bigB, bigB, Wb2,
        aff + 256, aff + 384, nullptr, ab2, nullptr, nullptr, nullptr, nullptr, stC);
    finalize_stats<<<1, 256, 0, stream>>>(stC, ag2, abe2, aff + 512, aff + 640);

    final_kernel<<<N_/4, 256, 0, stream>>>(bigA, bigB, aff + 0, aff + 128,
                                           aff + 512, aff + 640, xv, out);
}

// Round 5
// 333.748 us; speedup vs baseline: 2.2354x; 1.1607x over previous
//
#include <hip/hip_runtime.h>
#include <hip/hip_bf16.h>
#include <stdint.h>

#define B_ 8
#define P_ 2048
#define K_ 20
#define N_ (B_*P_)     // 16384
#define M_ (B_*K_)     // 160
#define C 128
#define E_ (N_*K_)     // 327680
#define EPS_ 1e-5f

typedef unsigned short u16;
typedef unsigned int u32;
typedef __attribute__((ext_vector_type(8))) short short8;
typedef __attribute__((ext_vector_type(4))) float floatx4;

__device__ __forceinline__ float bf2f(u16 u){
    union { u32 i; float f; } v; v.i = ((u32)u) << 16; return v.f;
}
__device__ __forceinline__ u16 f2bf(float f){
    union { float f; u32 i; } v; v.f = f;
    u32 r = ((v.i >> 16) & 1u) + 0x7fffu;
    return (u16)((v.i + r) >> 16);
}
__device__ __forceinline__ u32 pkbf(float a, float b){
    union { __hip_bfloat162 h; u32 u; } cv;
    cv.h = __float22bfloat162_rn(make_float2(a, b));
    return cv.u;
}

// ---------------------------------------------------------------------------
// prep: CqT = (aW1@Wq)^T [64,128], CkT = (aW1@Wk)^T, dq = aW1@bq + ab1,
//       dk = aW1@bk, WvT [64,128], frag-major bf16 copies of pW2, aW1, aW2.
// grid 69 x 256
__global__ __launch_bounds__(256)
void prep_weights(const float* __restrict__ Wq, const float* __restrict__ bq,
                  const float* __restrict__ Wk, const float* __restrict__ bk,
                  const float* __restrict__ aW1, const float* __restrict__ ab1,
                  const float* __restrict__ pW2, const float* __restrict__ aW2,
                  const float* __restrict__ Wv,
                  float* __restrict__ CqT, float* __restrict__ CkT,
                  float* __restrict__ dq, float* __restrict__ dk,
                  float* __restrict__ WvT,
                  u16* __restrict__ Wb0, u16* __restrict__ Wb1, u16* __restrict__ Wb2)
{
    int tid = threadIdx.x, blk = blockIdx.x;
    if (blk < 32) {
        int idx = blk*256 + tid; int o = idx >> 6, i = idx & 63;
        float s = 0.f;
        for (int cc = 0; cc < 128; ++cc) s = fmaf(aW1[o*128+cc], Wq[cc*64+i], s);
        CqT[i*128 + o] = s;
    } else if (blk < 64) {
        int idx = (blk-32)*256 + tid; int o = idx >> 6, i = idx & 63;
        float s = 0.f;
        for (int cc = 0; cc < 128; ++cc) s = fmaf(aW1[o*128+cc], Wk[cc*64+i], s);
        CkT[i*128 + o] = s;
    } else if (blk == 64) {
        if (tid < 128) {
            float s = ab1[tid];
            for (int cc = 0; cc < 128; ++cc) s = fmaf(aW1[tid*128+cc], bq[cc], s);
            dq[tid] = s;
        } else {
            int o = tid - 128;
            float s = 0.f;
            for (int cc = 0; cc < 128; ++cc) s = fmaf(aW1[o*128+cc], bk[cc], s);
            dk[o] = s;
        }
    } else if (blk == 68) {
        for (int idx = tid; idx < 8192; idx += 256) {
            int o = idx >> 6, i = idx & 63;
            WvT[i*128 + o] = Wv[idx];
        }
    } else {
        // frag-major remap: slot s = (ct*4+ks)*64 + lane, 8 u16 per slot.
        // frag element j = W[ct*16 + (lane&15)][ks*32 + (lane>>4)*8 + j]
        const float* src = (blk == 65) ? pW2 : (blk == 66) ? aW1 : aW2;
        u16* dst = (blk == 65) ? Wb0 : (blk == 66) ? Wb1 : Wb2;
        for (int s = tid; s < 2048; s += 256) {
            int ln = s & 63, ks = (s >> 6) & 3, ct = s >> 8;
            int Ls = ln & 15, qs = ln >> 4;
            const float* sp = src + (ct*16+Ls)*C + ks*32 + qs*8;
            #pragma unroll
            for (int j = 0; j < 8; ++j) dst[s*8+j] = f2bf(sp[j]);
        }
    }
}

// ---------------------------------------------------------------------------
// knn + kernel-weighted scatter into gacc[m][68] + per-graph pos moments.
// 64 points/block; wave 0 computes knn, all 4 waves scatter 16 points each.
// grid 256 x 256
__global__ __launch_bounds__(256)
void knn_scatter(const float* __restrict__ pos, const float* __restrict__ x,
                 const int* __restrict__ fps_idx, float* __restrict__ gacc,
                 float* __restrict__ posmom)
{
    __shared__ float fpos[K_][3];
    __shared__ float accL[K_*68];
    __shared__ int   skb[64];
    __shared__ float sek[64];
    int tid = threadIdx.x;
    int b = blockIdx.x >> 5;              // 32 blocks per graph
    if (tid < K_*3) {
        int k = tid / 3, d = tid - k*3;
        fpos[k][d] = pos[fps_idx[b*K_+k]*3 + d];
    }
    for (int i = tid; i < K_*68; i += 256) accL[i] = 0.f;
    __syncthreads();

    int wbase = blockIdx.x*64;
    if (tid < 64) {                       // wave 0: knn + pos parts + moments
        int p = wbase + tid;
        float px = pos[p*3], py = pos[p*3+1], pz = pos[p*3+2];
        float best = 1e30f; int kb = 0;
        #pragma unroll
        for (int k = 0; k < K_; ++k) {
            float dx = px - fpos[k][0], dy = py - fpos[k][1], dz = pz - fpos[k][2];
            float d2 = dx*dx + dy*dy + dz*dz;
            if (d2 < best) { best = d2; kb = k; }   // strict <: argmin keeps first
        }
        float ek = 1.0f / (1.0f + 5.0f*best);
        skb[tid] = kb; sek[tid] = ek;
        atomicAdd(&accL[kb*68 + 0], 1.0f);
        atomicAdd(&accL[kb*68 + 1], ek*px);
        atomicAdd(&accL[kb*68 + 2], ek*py);
        atomicAdd(&accL[kb*68 + 3], ek*pz);

        float mom[9] = {px,py,pz, px*px,px*py,px*pz, py*py,py*pz, pz*pz};
        #pragma unroll
        for (int i = 0; i < 9; ++i) {
            float v = mom[i];
            v += __shfl_xor(v,32); v += __shfl_xor(v,16); v += __shfl_xor(v,8);
            v += __shfl_xor(v,4);  v += __shfl_xor(v,2);  v += __shfl_xor(v,1);
            mom[i] = v;
        }
        if (tid == 0) {
            #pragma unroll
            for (int i = 0; i < 9; ++i) atomicAdd(&posmom[b*9+i], mom[i]);
        }
    }
    __syncthreads();

    // x scatter: wave w handles 16 points; lane = channel (coalesced reads,
    // LDS atomics over 64 consecutive floats: 2-way bank alias = free)
    int w = tid >> 6, lane = tid & 63;
    #pragma unroll
    for (int jj = 0; jj < 16; ++jj) {
        int j = w*16 + jj;
        int   kbj = skb[j];
        float ekj = sek[j];
        float xv = x[(size_t)(wbase+j)*64 + lane];
        atomicAdd(&accL[kbj*68 + 4 + lane], ekj*xv);
    }
    __syncthreads();
    for (int i = tid; i < K_*68; i += 256)
        atomicAdd(&gacc[b*K_*68 + i], accL[i]);
}

// divide sums by max(cnt,1) in place. grid 160 x 128
__global__ void fps_finalize(float* __restrict__ gacc)
{
    int m = blockIdx.x, t = threadIdx.x;
    float c = gacc[m*68]; c = c > 1.f ? c : 1.f;
    if (t >= 1 && t < 68) gacc[m*68+t] /= c;
}

// ---------------------------------------------------------------------------
// closed-form BN1 stats from rel moments; fold BN1+pW1 -> w3[4][128].
// single block x 256
__global__ __launch_bounds__(256)
void bn1_prep(const float* __restrict__ gacc, const float* __restrict__ posmom,
              const float* __restrict__ pW1, const float* __restrict__ pb1,
              const float* __restrict__ pg1, const float* __restrict__ pbe1,
              float* __restrict__ w3)
{
    __shared__ float sF[8][3], sG[8][6];
    __shared__ float S1[3], S2[6];
    int t = threadIdx.x;
    if (t < 8) {
        float F0=0,F1=0,F2=0,G0=0,G1=0,G2=0,G3=0,G4=0,G5=0;
        for (int k = 0; k < K_; ++k) {
            const float* f = gacc + (t*K_+k)*68 + 1;
            float x=f[0], y=f[1], z=f[2];
            F0+=x; F1+=y; F2+=z;
            G0+=x*x; G1+=x*y; G2+=x*z; G3+=y*y; G4+=y*z; G5+=z*z;
        }
        sF[t][0]=F0; sF[t][1]=F1; sF[t][2]=F2;
        sG[t][0]=G0; sG[t][1]=G1; sG[t][2]=G2; sG[t][3]=G3; sG[t][4]=G4; sG[t][5]=G5;
    }
    __syncthreads();
    if (t == 0) {
        float s1[3]={0,0,0}, s2[6]={0,0,0,0,0,0};
        for (int b = 0; b < 8; ++b) {
            const float* pm = posmom + b*9;
            float Ax=pm[0],Ay=pm[1],Az=pm[2];
            float Fx=sF[b][0],Fy=sF[b][1],Fz=sF[b][2];
            s1[0] += (float)K_*Ax - (float)P_*Fx;
            s1[1] += (float)K_*Ay - (float)P_*Fy;
            s1[2] += (float)K_*Az - (float)P_*Fz;
            s2[0] += (float)K_*pm[3] - 2.f*Ax*Fx + (float)P_*sG[b][0];
            s2[1] += (float)K_*pm[4] - Ax*Fy - Ay*Fx + (float)P_*sG[b][1];
            s2[2] += (float)K_*pm[5] - Ax*Fz - Az*Fx + (float)P_*sG[b][2];
            s2[3] += (float)K_*pm[6] - 2.f*Ay*Fy + (float)P_*sG[b][3];
            s2[4] += (float)K_*pm[7] - Ay*Fz - Az*Fy + (float)P_*sG[b][4];
            s2[5] += (float)K_*pm[8] - 2.f*Az*Fz + (float)P_*sG[b][5];
        }
        for (int i = 0; i < 3; ++i) S1[i] = s1[i];
        for (int i = 0; i < 6; ++i) S2[i] = s2[i];
    }
    __syncthreads();
    if (t < 128) {
        float w0=pW1[t*3], w1=pW1[t*3+1], w2=pW1[t*3+2], bb=pb1[t];
        float wS1 = w0*S1[0] + w1*S1[1] + w2*S1[2];
        float wS2w = w0*w0*S2[0] + w1*w1*S2[3] + w2*w2*S2[5]
                   + 2.f*(w0*w1*S2[1] + w0*w2*S2[2] + w1*w2*S2[4]);
        const float invE = 1.0f/(float)E_;
        float m1  = wS1*invE + bb;
        float Ez2 = (wS2w + 2.f*bb*wS1)*invE + bb*bb;
        float var = Ez2 - m1*m1;
        float sc = pg1[t] * rsqrtf(var + EPS_);
        float sh = pbe1[t] - m1*sc;
        w3[0*128+t] = w0*sc; w3[1*128+t] = w1*sc;
        w3[2*128+t] = w2*sc; w3[3*128+t] = bb*sc + sh;
    }
}

// Ak2[m] = CkT^T@fps_x + dk ; xv[m] = WvT^T@fps_x + bv. grid 160 x 128
__global__ __launch_bounds__(128)
void proj_m(const float* __restrict__ gacc, const float* __restrict__ CkT,
            const float* __restrict__ dk, const float* __restrict__ WvT,
            const float* __restrict__ bv, float* __restrict__ Ak2,
            float* __restrict__ xv)
{
    int m = blockIdx.x, o = threadIdx.x;
    const float* fx = gacc + m*68 + 4;
    float a = dk[o], v = bv[o];
    for (int i = 0; i < 64; ++i) {
        float xi = fx[i];                       // wave-uniform (scalarizable)
        a = fmaf(CkT[i*128+o], xi, a);          // coalesced
        v = fmaf(WvT[i*128+o], xi, v);          // coalesced
    }
    Ak2[m*C+o] = a; xv[m*C+o] = v;
}

// Aq2[p] = CqT^T@x[p] + dq. 8 points/block, coalesced CqT reads.
// grid 2048 x 256
__global__ __launch_bounds__(256)
void proj_q(const float* __restrict__ x, const float* __restrict__ CqT,
            const float* __restrict__ dq, float* __restrict__ Aq2)
{
    __shared__ float xs[512];                   // 8 points x 64 ch (contiguous)
    int tid = threadIdx.x;
    int p0 = blockIdx.x*8;
    const float* xp = x + (size_t)p0*64;
    for (int i = tid; i < 512; i += 256) xs[i] = xp[i];
    __syncthreads();
    int g = tid >> 7, o = tid & 127;
    const float* xb = xs + g*256;               // this half's 4 points
    float d = dq[o];
    float a0=d, a1=d, a2=d, a3=d;
    #pragma unroll 4
    for (int i = 0; i < 64; ++i) {
        float w = CqT[i*128 + o];               // coalesced, L2-resident
        a0 = fmaf(w, xb[i],       a0);
        a1 = fmaf(w, xb[64+i],    a1);
        a2 = fmaf(w, xb[128+i],   a2);
        a3 = fmaf(w, xb[192+i],   a3);
    }
    int pb = p0 + g*4;
    Aq2[(size_t)(pb+0)*C + o] = a0;
    Aq2[(size_t)(pb+1)*C + o] = a1;
    Aq2[(size_t)(pb+2)*C + o] = a2;
    Aq2[(size_t)(pb+3)*C + o] = a3;
}

// reduce 32 stat replicas, then scale = g*rsqrt(var+eps); shift = be - mean*sc.
// 1 block x 256
__global__ __launch_bounds__(256)
void finalize_stats(const float* __restrict__ stats32,
                    const float* __restrict__ g, const float* __restrict__ be,
                    float* __restrict__ scale, float* __restrict__ shift)
{
    __shared__ float red[256];
    int tid = threadIdx.x;
    float s = 0.f;
    for (int r = 0; r < 32; ++r) s += stats32[r*256 + tid];
    red[tid] = s;
    __syncthreads();
    if (tid < C) {
        float mean = red[tid] * (1.0f/E_);
        float var  = red[C+tid] * (1.0f/E_) - mean*mean;
        float sc = g[tid] * rsqrtf(var + EPS_);
        scale[tid] = sc;
        shift[tid] = be[tid] - mean*sc;
    }
}

// ---------------------------------------------------------------------------
// Fused GEMM v4: two 16-row tiles per wave (ILP), B-frags loaded once per ks
// and shared by both tiles; no block barrier in the hot path.
// out[e,:] = A(e,:) @ Wb^T (+bias) (+Aq2[p]-Ak2[m]); bf16 direct stores;
// fused per-channel sum/sumsq -> 32-way-replicated global stats.
// MODE 0: A = relu(BN1-folded pos-MLP layer1) on the fly
// MODE 1: A = relu(zin*sc+sh); epilogue += Aq2[p]-Ak2[m]
// MODE 2: A = relu(zin*sc+sh); epilogue += bias
// grid 2560 x 256 (4 waves x 2 tiles x 16 rows = 128 rows/block)
template<int MODE>
__global__ __launch_bounds__(256)
void gemm_fused(const u16* __restrict__ zin, u16* __restrict__ zout,
                const u16* __restrict__ Wbf,
                const float* __restrict__ scale, const float* __restrict__ shift,
                const float* __restrict__ w3,
                const float* __restrict__ bias,
                const float* __restrict__ rowq, const float* __restrict__ rowk,
                const float* __restrict__ pos, const float* __restrict__ gacc,
                float* __restrict__ stats32)
{
    __shared__ float s_stat[2][C];      // 1 KB
    __shared__ float saff[5*C];         // 2.5 KB affine params

    int tid = threadIdx.x;
    const int wave = tid >> 6, lane = tid & 63;
    const int L = lane & 15, q = lane >> 4;

    ((float*)s_stat)[tid] = 0.f;
    if constexpr (MODE == 0) {
        for (int i = tid; i < 512; i += 256) saff[i] = w3[i];
        if (tid < C) saff[512+tid] = bias[tid];
    } else {
        if (tid < C) { saff[tid] = scale[tid]; saff[C+tid] = shift[tid]; }
        if constexpr (MODE == 2) { if (tid < C) saff[2*C+tid] = bias[tid]; }
    }
    __syncthreads();

    int tbs[2];
    tbs[0] = (blockIdx.x*8 + wave)*16;
    tbs[1] = (blockIdx.x*8 + wave + 4)*16;

    short8 An[2][4];
    float rr0[2], rr1[2], rr2[2];
    #pragma unroll
    for (int tt = 0; tt < 2; ++tt) {
        if constexpr (MODE != 0) {
            const u16* ap = zin + (size_t)(tbs[tt] + L)*C + q*8;
            An[tt][0] = *(const short8*)ap;
            An[tt][1] = *(const short8*)(ap + 32);
            An[tt][2] = *(const short8*)(ap + 64);
            An[tt][3] = *(const short8*)(ap + 96);
        } else {
            unsigned e = (unsigned)(tbs[tt] + L);
            unsigned p = e / 20u; int k = (int)(e - p*20u);
            int m = (int)(p >> 11)*20 + k;
            const float* fp = gacc + m*68 + 1;
            rr0[tt] = pos[p*3]   - fp[0];
            rr1[tt] = pos[p*3+1] - fp[1];
            rr2[tt] = pos[p*3+2] - fp[2];
        }
    }

    floatx4 acc[2][8];
    #pragma unroll
    for (int tt = 0; tt < 2; ++tt)
        #pragma unroll
        for (int ct = 0; ct < 8; ++ct) acc[tt][ct] = (floatx4){0.f,0.f,0.f,0.f};

    #pragma unroll
    for (int ks = 0; ks < 4; ++ks) {
        int ch0 = ks*32 + q*8;
        short8 bfr[8];
        #pragma unroll
        for (int ct = 0; ct < 8; ++ct)
            bfr[ct] = *(const short8*)(Wbf + ((ct*4+ks)*64 + lane)*8);
        #pragma unroll
        for (int tt = 0; tt < 2; ++tt) {
            union { short8 s8; u32 u[4]; } af;
            if constexpr (MODE == 0) {
                #pragma unroll
                for (int jj = 0; jj < 4; ++jj) {
                    int c0 = ch0 + jj*2, c1 = ch0 + jj*2 + 1;
                    float f0 = fmaf(saff[c0], rr0[tt], fmaf(saff[C+c0], rr1[tt],
                               fmaf(saff[2*C+c0], rr2[tt], saff[3*C+c0])));
                    float f1 = fmaf(saff[c1], rr0[tt], fmaf(saff[C+c1], rr1[tt],
                               fmaf(saff[2*C+c1], rr2[tt], saff[3*C+c1])));
                    f0 = f0 > 0.f ? f0 : 0.f;
                    f1 = f1 > 0.f ? f1 : 0.f;
                    af.u[jj] = pkbf(f0, f1);
                }
            } else {
                short8 ar = An[tt][ks];
                #pragma unroll
                for (int jj = 0; jj < 4; ++jj) {
                    int c0 = ch0 + jj*2, c1 = ch0 + jj*2 + 1;
                    float f0 = fmaf(bf2f((u16)ar[jj*2]),   saff[c0], saff[C+c0]);
                    float f1 = fmaf(bf2f((u16)ar[jj*2+1]), saff[c1], saff[C+c1]);
                    f0 = f0 > 0.f ? f0 : 0.f;
                    f1 = f1 > 0.f ? f1 : 0.f;
                    af.u[jj] = pkbf(f0, f1);
                }
            }
            #pragma unroll
            for (int ct = 0; ct < 8; ++ct)
                acc[tt][ct] = __builtin_amdgcn_mfma_f32_16x16x32_bf16(af.s8, bfr[ct], acc[tt][ct], 0, 0, 0);
        }
    }

    // epilogue: bias / qmk adds, fused stats, direct bf16 stores
    float ssum[8], ssq[8];
    #pragma unroll
    for (int i = 0; i < 8; ++i) { ssum[i] = 0.f; ssq[i] = 0.f; }

    #pragma unroll
    for (int tt = 0; tt < 2; ++tt) {
        const int tilebase = tbs[tt];
        int pp[4], mm[4];
        if constexpr (MODE == 1) {
            #pragma unroll
            for (int r = 0; r < 4; ++r) {
                unsigned e2 = (unsigned)(tilebase + q*4 + r);
                unsigned p2 = e2 / 20u; int k2 = (int)(e2 - p2*20u);
                pp[r] = (int)p2; mm[r] = (int)(p2 >> 11)*20 + k2;
            }
        }
        u16* orow = zout + (size_t)(tilebase + q*4)*C + L;
        #pragma unroll
        for (int ct = 0; ct < 8; ++ct) {
            int col = ct*16 + L;
            float bb;
            if constexpr (MODE == 0) bb = saff[4*C + col];
            else if constexpr (MODE == 2) bb = saff[2*C + col];
            else bb = 0.f;
            #pragma unroll
            for (int r = 0; r < 4; ++r) {
                float z = acc[tt][ct][r] + bb;
                if constexpr (MODE == 1)
                    z += rowq[pp[r]*C + col] - rowk[mm[r]*C + col];
                ssum[ct] += z; ssq[ct] += z*z;
                orow[(size_t)r*C + ct*16] = (u16)pkbf(z, z);
            }
        }
    }

    // stats: reduce over q-groups via shuffles, LDS accumulate, one replica-
    // atomic burst per block
    #pragma unroll
    for (int ct = 0; ct < 8; ++ct) {
        float v = ssum[ct]; v += __shfl_xor(v,16); v += __shfl_xor(v,32);
        float w = ssq[ct];  w += __shfl_xor(w,16); w += __shfl_xor(w,32);
        if (lane < 16) {
            atomicAdd(&s_stat[0][ct*16+L], v);
            atomicAdd(&s_stat[1][ct*16+L], w);
        }
    }
    __syncthreads();
    float* dst = stats32 + ((blockIdx.x & 31) << 8);
    atomicAdd(&dst[tid], ((float*)s_stat)[tid]);
}

// ---------------------------------------------------------------------------
// final: alpha = softmax_k(relu(affine4(za2))); delta = relu(affine2(z2));
// out[p,c] = sum_k alpha*(xv[m,c]+delta). Online (max-free: relu(BN'd) values
// are O(1), exp safe in fp32). 2 channels/lane, 4 points/block. grid 4096x256
__global__ __launch_bounds__(256)
void final_kernel(const u16* __restrict__ z2, const u16* __restrict__ za2,
                  const float* __restrict__ sc2, const float* __restrict__ sh2,
                  const float* __restrict__ sc4, const float* __restrict__ sh4,
                  const float* __restrict__ xv, float* __restrict__ out)
{
    int tid = threadIdx.x;
    int p = blockIdx.x*4 + (tid >> 6);
    int lane = tid & 63;
    int c2 = lane*2;
    int b = p >> 11;
    float S2x=sc2[c2], S2y=sc2[c2+1], H2x=sh2[c2], H2y=sh2[c2+1];
    float S4x=sc4[c2], S4y=sc4[c2+1], H4x=sh4[c2], H4y=sh4[c2+1];
    size_t ebase = (size_t)p * K_;
    const float* xvb = xv + (size_t)(b*K_)*C + c2;
    float l0 = 0.f, l1 = 0.f, o0 = 0.f, o1 = 0.f;
    #pragma unroll
    for (int k = 0; k < K_; ++k) {
        u32 wa = *(const u32*)(za2 + (ebase+k)*C + c2);
        u32 wz = *(const u32*)(z2  + (ebase+k)*C + c2);
        float2 xvv = *(const float2*)(xvb + (size_t)k*C);
        float aa0 = fmaf(bf2f((u16)(wa & 0xffffu)), S4x, H4x); aa0 = aa0 > 0.f ? aa0 : 0.f;
        float aa1 = fmaf(bf2f((u16)(wa >> 16)),     S4y, H4y); aa1 = aa1 > 0.f ? aa1 : 0.f;
        float dd0 = fmaf(bf2f((u16)(wz & 0xffffu)), S2x, H2x); dd0 = dd0 > 0.f ? dd0 : 0.f;
        float dd1 = fmaf(bf2f((u16)(wz >> 16)),     S2y, H2y); dd1 = dd1 > 0.f ? dd1 : 0.f;
        float e0 = __expf(aa0), e1 = __expf(aa1);
        l0 += e0; l1 += e1;
        o0 = fmaf(e0, xvv.x + dd0, o0);
        o1 = fmaf(e1, xvv.y + dd1, o1);
    }
    out[(size_t)p*C + c2]     = o0 / l0;
    out[(size_t)p*C + c2 + 1] = o1 / l1;
}

// ---------------------------------------------------------------------------
extern "C" void kernel_launch(void* const* d_in, const int* in_sizes, int n_in,
                              void* d_out, int out_size, void* d_ws, size_t ws_size,
                              hipStream_t stream)
{
    const float* x    = (const float*)d_in[0];
    const float* pos  = (const float*)d_in[1];
    const float* Wq   = (const float*)d_in[2];
    const float* bq   = (const float*)d_in[3];
    const float* Wk   = (const float*)d_in[4];
    const float* bk   = (const float*)d_in[5];
    const float* Wv   = (const float*)d_in[6];
    const float* bv   = (const float*)d_in[7];
    const float* pW1  = (const float*)d_in[8];
    const float* pb1  = (const float*)d_in[9];
    const float* pg1  = (const float*)d_in[10];
    const float* pbe1 = (const float*)d_in[11];
    const float* pW2  = (const float*)d_in[12];
    const float* pb2  = (const float*)d_in[13];
    const float* pg2  = (const float*)d_in[14];
    const float* pbe2 = (const float*)d_in[15];
    const float* aW1  = (const float*)d_in[16];
    const float* ab1  = (const float*)d_in[17];
    const float* ag1  = (const float*)d_in[18];
    const float* abe1 = (const float*)d_in[19];
    const float* aW2  = (const float*)d_in[20];
    const float* ab2  = (const float*)d_in[21];
    const float* ag2  = (const float*)d_in[22];
    const float* abe2 = (const float*)d_in[23];
    const int* fps_idx = (const int*)d_in[24];
    float* out = (float*)d_out;

    char* ws = (char*)d_ws;
    size_t off = 0;
    auto alloc = [&](size_t bytes) -> void* {
        void* r = ws + off;
        off = (off + bytes + 255) & ~(size_t)255;
        return r;
    };
    float* gacc    = (float*)alloc(160*68*4);        // zeroed
    float* posmom  = (float*)alloc(8*9*4);           // zeroed
    float* stats32 = (float*)alloc(3*32*256*4);      // zeroed (3 layers x 32 reps)
    size_t zero_bytes = off;
    float* aff = (float*)alloc(6*128*4);             // sc2,sh2,sc3,sh3,sc4,sh4
    float* w3  = (float*)alloc(4*128*4);
    float* CqT = (float*)alloc(64*128*4);
    float* CkT = (float*)alloc(64*128*4);
    float* dq  = (float*)alloc(128*4);
    float* dk  = (float*)alloc(128*4);
    float* WvT = (float*)alloc(64*128*4);
    u16* Wb0   = (u16*)alloc(128*128*2);             // frag-major
    u16* Wb1   = (u16*)alloc(128*128*2);
    u16* Wb2   = (u16*)alloc(128*128*2);
    float* Aq2 = (float*)alloc((size_t)N_*128*4);
    float* Ak2 = (float*)alloc(160*128*4);
    float* xv  = (float*)alloc(160*128*4);
    u16* bigA  = (u16*)alloc((size_t)E_*128*2);      // z2
    u16* bigB  = (u16*)alloc((size_t)E_*128*2);      // za1 -> za2 (in place)

    hipMemsetAsync(d_ws, 0, zero_bytes, stream);

    prep_weights<<<69, 256, 0, stream>>>(Wq, bq, Wk, bk, aW1, ab1, pW2, aW2, Wv,
                                         CqT, CkT, dq, dk, WvT, Wb0, Wb1, Wb2);
    knn_scatter<<<256, 256, 0, stream>>>(pos, x, fps_idx, gacc, posmom);
    fps_finalize<<<160, 128, 0, stream>>>(gacc);
    bn1_prep<<<1, 256, 0, stream>>>(gacc, posmom, pW1, pb1, pg1, pbe1, w3);
    proj_m<<<160, 128, 0, stream>>>(gacc, CkT, dk, WvT, bv, Ak2, xv);
    proj_q<<<N_/8, 256, 0, stream>>>(x, CqT, dq, Aq2);

    float* stA = stats32;
    float* stB = stats32 + 32*256;
    float* stC = stats32 + 2*32*256;

    // gemm1: rel -> z2 (bias pb2), stats of z2
    gemm_fused<0><<<E_/128, 256, 0, stream>>>(nullptr, bigA, Wb0,
        nullptr, nullptr, w3, pb2, nullptr, nullptr, pos, gacc, stA);
    finalize_stats<<<1, 256, 0, stream>>>(stA, pg2, pbe2, aff + 0, aff + 128);

    // gemm2: z2 -> za1 (+Aq2-Ak2), stats of za1
    gemm_fused<1><<<E_/128, 256, 0, stream>>>(bigA, bigB, Wb1,
        aff + 0, aff + 128, nullptr, nullptr, Aq2, Ak2, nullptr, nullptr, stB);
    finalize_stats<<<1, 256, 0, stream>>>(stB, ag1, abe1, aff + 256, aff + 384);

    // gemm3: za1 -> za2 (bias ab2), stats of za2
    gemm_fused<2><<<E_/128, 256, 0, stream>>>(bigB, bigB, Wb2,
        aff + 256, aff + 384, nullptr, ab2, nullptr, nullptr, nullptr, nullptr, stC);
    finalize_stats<<<1, 256, 0, stream>>>(stC, ag2, abe2, aff + 512, aff + 640);

    final_kernel<<<N_/4, 256, 0, stream>>>(bigA, bigB, aff + 0, aff + 128,
                                           aff + 512, aff + 640, xv, out);
}